// Round 1
// baseline (526.005 us; speedup 1.0000x reference)
//
#include <hip/hip_runtime.h>
#include <hip/hip_bf16.h>
#include <math.h>

// Problem constants
#define S 2048
#define HID 2048
#define NH 16
#define KVH 8
#define HD 128
#define EPS 1e-6f
#define QK_SCALE 11.313708498984760390f  // 1/SCALING = sqrt(128)

typedef __attribute__((ext_vector_type(8))) short s16x8;
typedef __attribute__((ext_vector_type(4))) float f32x4;

__device__ __forceinline__ unsigned short f2bf(float f) {
  __hip_bfloat16 h = __float2bfloat16(f);
  return *(unsigned short*)&h;
}
__device__ __forceinline__ float bf2f(unsigned short u) {
  unsigned int x = ((unsigned int)u) << 16;
  return __builtin_bit_cast(float, x);
}

__device__ __forceinline__ void gload16(const void* g, void* l) {
  __builtin_amdgcn_global_load_lds(
      (const __attribute__((address_space(1))) void*)g,
      (__attribute__((address_space(3))) void*)l, 16, 0, 0);
}

// ---------------------------------------------------------------------------
// fp32 -> split bf16 (hi + lo) elementwise.
// ---------------------------------------------------------------------------
__global__ __launch_bounds__(256) void f32_to_bf16_split(const float* __restrict__ in,
                                                         unsigned short* __restrict__ hi,
                                                         unsigned short* __restrict__ lo,
                                                         int n4) {
  const int i = blockIdx.x * 256 + threadIdx.x;
  if (i < n4) {
    const float4 v = *(const float4*)(in + (size_t)i * 4);
    ushort4 h, l;
    h.x = f2bf(v.x); l.x = f2bf(v.x - bf2f(h.x));
    h.y = f2bf(v.y); l.y = f2bf(v.y - bf2f(h.y));
    h.z = f2bf(v.z); l.z = f2bf(v.z - bf2f(h.z));
    h.w = f2bf(v.w); l.w = f2bf(v.w - bf2f(h.w));
    *(ushort4*)(hi + (size_t)i * 4) = h;
    *(ushort4*)(lo + (size_t)i * 4) = l;
  }
}

// ---------------------------------------------------------------------------
// Transpose fp32 [K][N] -> bf16 [N][K], plain.
// ---------------------------------------------------------------------------
__global__ __launch_bounds__(256) void transpose_to_bf16(const float* __restrict__ in,
                                                         unsigned short* __restrict__ out,
                                                         int K, int N) {
  __shared__ float t[64][65];
  const int n0 = blockIdx.x * 64;
  const int k0 = blockIdx.y * 64;
  const int tid = threadIdx.x;

  for (int idx = tid; idx < 64 * 16; idx += 256) {
    const int r = idx >> 4;
    const int c4 = (idx & 15) * 4;
    const float4 v = *(const float4*)(in + (size_t)(k0 + r) * N + n0 + c4);
    t[r][c4 + 0] = v.x; t[r][c4 + 1] = v.y; t[r][c4 + 2] = v.z; t[r][c4 + 3] = v.w;
  }
  __syncthreads();
  for (int idx = tid; idx < 64 * 16; idx += 256) {
    const int a = idx >> 4;
    const int b4 = (idx & 15) * 4;
    ushort4 u;
    u.x = f2bf(t[b4 + 0][a]); u.y = f2bf(t[b4 + 1][a]);
    u.z = f2bf(t[b4 + 2][a]); u.w = f2bf(t[b4 + 3][a]);
    *(ushort4*)(out + (size_t)(n0 + a) * K + k0 + b4) = u;
  }
}

// ---------------------------------------------------------------------------
// Transpose fp32 [K][N] -> split bf16 hi/lo [N][K].
// ---------------------------------------------------------------------------
__global__ __launch_bounds__(256) void transpose_to_bf16_split(const float* __restrict__ in,
                                                               unsigned short* __restrict__ ohi,
                                                               unsigned short* __restrict__ olo,
                                                               int K, int N) {
  __shared__ float t[64][65];
  const int n0 = blockIdx.x * 64;
  const int k0 = blockIdx.y * 64;
  const int tid = threadIdx.x;

  for (int idx = tid; idx < 64 * 16; idx += 256) {
    const int r = idx >> 4;
    const int c4 = (idx & 15) * 4;
    const float4 v = *(const float4*)(in + (size_t)(k0 + r) * N + n0 + c4);
    t[r][c4 + 0] = v.x; t[r][c4 + 1] = v.y; t[r][c4 + 2] = v.z; t[r][c4 + 3] = v.w;
  }
  __syncthreads();
  for (int idx = tid; idx < 64 * 16; idx += 256) {
    const int a = idx >> 4;
    const int b4 = (idx & 15) * 4;
    ushort4 h, l;
#pragma unroll
    for (int q = 0; q < 4; ++q) {
      const float v = t[b4 + q][a];
      const unsigned short hu = f2bf(v);
      const unsigned short lu = f2bf(v - bf2f(hu));
      ((unsigned short*)&h)[q] = hu;
      ((unsigned short*)&l)[q] = lu;
    }
    *(ushort4*)(ohi + (size_t)(n0 + a) * K + k0 + b4) = h;
    *(ushort4*)(olo + (size_t)(n0 + a) * K + k0 + b4) = l;
  }
}

// ---------------------------------------------------------------------------
// Plain bf16 MFMA GEMM (m97 structure): C[M][ldc] = A[M][K] * Bt[N][K]^T.
// 128x128 tile.
// ---------------------------------------------------------------------------
#define BM 128
#define BN 128
#define BK 32

template <typename OT>
__global__ __launch_bounds__(256) void gemm_bf16_bt(const unsigned short* __restrict__ A,
                                                    const unsigned short* __restrict__ Bt,
                                                    OT* __restrict__ C,
                                                    int M, int N, int K, int ldc) {
  __shared__ unsigned short As[BM * BK];
  __shared__ unsigned short Bs[BN * BK];

  const int tid = threadIdx.x;
  const int lane = tid & 63;
  const int wave = tid >> 6;
  const int m0 = blockIdx.y * BM;
  const int n0 = blockIdx.x * BN;

  const int qm = (wave >> 1) * 64;
  const int qn = (wave & 1) * 64;
  const int l15 = lane & 15;
  const int quad = lane >> 4;

  const int st_row = lane >> 2;
  const int st_col = (lane & 3) * 8;

  f32x4 acc[4][4] = {};

  for (int k0 = 0; k0 < K; k0 += BK) {
#pragma unroll
    for (int p = 0; p < 2; ++p) {
      const int rb = p * 64 + wave * 16;
      gload16(A + (size_t)(m0 + rb + st_row) * K + k0 + st_col, &As[rb * BK]);
      gload16(Bt + (size_t)(n0 + rb + st_row) * K + k0 + st_col, &Bs[rb * BK]);
    }
    __syncthreads();

    s16x8 a[4], b[4];
#pragma unroll
    for (int i = 0; i < 4; ++i)
      a[i] = *(const s16x8*)&As[(qm + i * 16 + l15) * BK + quad * 8];
#pragma unroll
    for (int j = 0; j < 4; ++j)
      b[j] = *(const s16x8*)&Bs[(qn + j * 16 + l15) * BK + quad * 8];
#pragma unroll
    for (int i = 0; i < 4; ++i)
#pragma unroll
      for (int j = 0; j < 4; ++j)
        acc[i][j] = __builtin_amdgcn_mfma_f32_16x16x32_bf16(a[i], b[j], acc[i][j], 0, 0, 0);
    __syncthreads();
  }

#pragma unroll
  for (int i = 0; i < 4; ++i) {
    const int row_base = m0 + qm + i * 16 + quad * 4;
#pragma unroll
    for (int j = 0; j < 4; ++j) {
      const int col = n0 + qn + j * 16 + l15;
#pragma unroll
      for (int r = 0; r < 4; ++r) {
        if constexpr (sizeof(OT) == 2)
          C[(size_t)(row_base + r) * ldc + col] = (OT)f2bf(acc[i][j][r]);
        else
          C[(size_t)(row_base + r) * ldc + col] = acc[i][j][r];
      }
    }
  }
}

// ---------------------------------------------------------------------------
// 128x64-tile bf16 MFMA GEMM for grid-starved shapes (V proj, wo proj).
// MODE 0: float C store. MODE 1: transposed bf16 store Ct[n][ldct]+m.
// 256 threads, 4 waves in 2x2 quadrants of 64x32.
// ---------------------------------------------------------------------------
template <int MODE, typename OT>
__global__ __launch_bounds__(256) void gemm_bf16_bt64(const unsigned short* __restrict__ A,
                                                      const unsigned short* __restrict__ Bt,
                                                      OT* __restrict__ C,
                                                      int M, int N, int K, int ldc) {
  __shared__ unsigned short As[BM * BK];
  __shared__ unsigned short Bs[64 * BK];

  const int tid = threadIdx.x;
  const int lane = tid & 63;
  const int wave = tid >> 6;
  const int m0 = blockIdx.y * BM;
  const int n0 = blockIdx.x * 64;

  const int qm = (wave >> 1) * 64;
  const int qn = (wave & 1) * 32;
  const int l15 = lane & 15;
  const int quad = lane >> 4;

  const int st_row = lane >> 2;
  const int st_col = (lane & 3) * 8;

  f32x4 acc[4][2] = {};

  for (int k0 = 0; k0 < K; k0 += BK) {
#pragma unroll
    for (int p = 0; p < 2; ++p) {
      const int rb = p * 64 + wave * 16;
      gload16(A + (size_t)(m0 + rb + st_row) * K + k0 + st_col, &As[rb * BK]);
    }
    {
      const int rb = wave * 16;
      gload16(Bt + (size_t)(n0 + rb + st_row) * K + k0 + st_col, &Bs[rb * BK]);
    }
    __syncthreads();

    s16x8 a[4], b[2];
#pragma unroll
    for (int i = 0; i < 4; ++i)
      a[i] = *(const s16x8*)&As[(qm + i * 16 + l15) * BK + quad * 8];
#pragma unroll
    for (int j = 0; j < 2; ++j)
      b[j] = *(const s16x8*)&Bs[(qn + j * 16 + l15) * BK + quad * 8];
#pragma unroll
    for (int i = 0; i < 4; ++i)
#pragma unroll
      for (int j = 0; j < 2; ++j)
        acc[i][j] = __builtin_amdgcn_mfma_f32_16x16x32_bf16(a[i], b[j], acc[i][j], 0, 0, 0);
    __syncthreads();
  }

#pragma unroll
  for (int i = 0; i < 4; ++i) {
    const int row_base = m0 + qm + i * 16 + quad * 4;
#pragma unroll
    for (int j = 0; j < 2; ++j) {
      const int col = n0 + qn + j * 16 + l15;
      if constexpr (MODE == 0) {
#pragma unroll
        for (int r = 0; r < 4; ++r)
          C[(size_t)(row_base + r) * ldc + col] = acc[i][j][r];
      } else {
        ushort4 u;
        u.x = f2bf(acc[i][j][0]); u.y = f2bf(acc[i][j][1]);
        u.z = f2bf(acc[i][j][2]); u.w = f2bf(acc[i][j][3]);
        *(ushort4*)((unsigned short*)C + (size_t)col * ldc + row_base) = u;
      }
    }
  }
}

// ---------------------------------------------------------------------------
// Split-precision bf16 MFMA GEMM: C = (Ahi+Alo) * (Bhi+Blo)^T, dropping lo*lo.
// ---------------------------------------------------------------------------
__global__ __launch_bounds__(256) void gemm_split_bt(const unsigned short* __restrict__ Ahi,
                                                     const unsigned short* __restrict__ Alo,
                                                     const unsigned short* __restrict__ Bhi,
                                                     const unsigned short* __restrict__ Blo,
                                                     float* __restrict__ C,
                                                     int M, int N, int K, int ldc) {
  __shared__ unsigned short AsH[BM * BK];
  __shared__ unsigned short AsL[BM * BK];
  __shared__ unsigned short BsH[BN * BK];
  __shared__ unsigned short BsL[BN * BK];

  const int tid = threadIdx.x;
  const int lane = tid & 63;
  const int wave = tid >> 6;
  const int m0 = blockIdx.y * BM;
  const int n0 = blockIdx.x * BN;

  const int qm = (wave >> 1) * 64;
  const int qn = (wave & 1) * 64;
  const int l15 = lane & 15;
  const int quad = lane >> 4;

  const int st_row = lane >> 2;
  const int st_col = (lane & 3) * 8;

  f32x4 acc[4][4] = {};

  for (int k0 = 0; k0 < K; k0 += BK) {
#pragma unroll
    for (int p = 0; p < 2; ++p) {
      const int rb = p * 64 + wave * 16;
      const size_t aoff = (size_t)(m0 + rb + st_row) * K + k0 + st_col;
      const size_t boff = (size_t)(n0 + rb + st_row) * K + k0 + st_col;
      gload16(Ahi + aoff, &AsH[rb * BK]);
      gload16(Alo + aoff, &AsL[rb * BK]);
      gload16(Bhi + boff, &BsH[rb * BK]);
      gload16(Blo + boff, &BsL[rb * BK]);
    }
    __syncthreads();

    s16x8 ah[4], al[4], bh[4], bl[4];
#pragma unroll
    for (int i = 0; i < 4; ++i) {
      const int ro = (qm + i * 16 + l15) * BK + quad * 8;
      ah[i] = *(const s16x8*)&AsH[ro];
      al[i] = *(const s16x8*)&AsL[ro];
    }
#pragma unroll
    for (int j = 0; j < 4; ++j) {
      const int ro = (qn + j * 16 + l15) * BK + quad * 8;
      bh[j] = *(const s16x8*)&BsH[ro];
      bl[j] = *(const s16x8*)&BsL[ro];
    }
#pragma unroll
    for (int i = 0; i < 4; ++i)
#pragma unroll
      for (int j = 0; j < 4; ++j) {
        acc[i][j] = __builtin_amdgcn_mfma_f32_16x16x32_bf16(ah[i], bh[j], acc[i][j], 0, 0, 0);
        acc[i][j] = __builtin_amdgcn_mfma_f32_16x16x32_bf16(ah[i], bl[j], acc[i][j], 0, 0, 0);
        acc[i][j] = __builtin_amdgcn_mfma_f32_16x16x32_bf16(al[i], bh[j], acc[i][j], 0, 0, 0);
      }
    __syncthreads();
  }

#pragma unroll
  for (int i = 0; i < 4; ++i) {
    const int row_base = m0 + qm + i * 16 + quad * 4;
#pragma unroll
    for (int j = 0; j < 4; ++j) {
      const int col = n0 + qn + j * 16 + l15;
#pragma unroll
      for (int r = 0; r < 4; ++r)
        C[(size_t)(row_base + r) * ldc + col] = acc[i][j][r];
    }
  }
}

// ---------------------------------------------------------------------------
// Fused RMSNorm + RoPE, wave-per-row shfl version (no LDS, no barriers).
// ---------------------------------------------------------------------------
__global__ __launch_bounds__(256) void rmsnorm_rope_split(const float* __restrict__ qk,
                                                          const float* __restrict__ cosb,
                                                          const float* __restrict__ sinb,
                                                          unsigned short* __restrict__ qh,
                                                          unsigned short* __restrict__ ql,
                                                          unsigned short* __restrict__ kh,
                                                          unsigned short* __restrict__ kl) {
  const int s = blockIdx.x;
  const int wave = threadIdx.x >> 6;
  const int lane = threadIdx.x & 63;
  const int hh = blockIdx.y * 4 + wave;
  const bool is_q = (hh < 16);
  const int col = is_q ? hh * HD : 2048 + (hh - 16) * HD;

  const float* row = qk + (size_t)s * 3072 + col;
  const float x1 = row[lane];
  const float x2 = row[lane + 64];

  float ss = x1 * x1 + x2 * x2;
  ss += __shfl_xor(ss, 1);
  ss += __shfl_xor(ss, 2);
  ss += __shfl_xor(ss, 4);
  ss += __shfl_xor(ss, 8);
  ss += __shfl_xor(ss, 16);
  ss += __shfl_xor(ss, 32);
  const float r = rsqrtf(ss / 128.f + EPS);

  const float c = cosb[(size_t)s * HD + lane];
  const float sn = sinb[(size_t)s * HD + lane];
  float o1 = x1 * r * c - x2 * r * sn;   // d = lane
  float o2 = x2 * r * c + x1 * r * sn;   // d = lane + 64
  if (is_q) { o1 *= QK_SCALE; o2 *= QK_SCALE; }

  const unsigned short h1 = f2bf(o1), l1 = f2bf(o1 - bf2f(h1));
  const unsigned short h2 = f2bf(o2), l2 = f2bf(o2 - bf2f(h2));
  if (is_q) {
    const size_t base = (size_t)s * 2048 + hh * HD + lane;
    qh[base] = h1; ql[base] = l1;
    qh[base + 64] = h2; ql[base + 64] = l2;
  } else {
    const size_t base = (size_t)s * 1024 + (hh - 16) * HD + lane;
    kh[base] = h1; kl[base] = l1;
    kh[base + 64] = h2; kl[base + 64] = l2;
  }
}

// ---------------------------------------------------------------------------
// Flash attention, MFMA, 2x2 wave partition + swizzled LDS.
// THIS ROUND (latency-bound per rocprof: MfmaUtil 21.6 / VALUBusy 29.8 /
// HBM 6.6% / 2 blocks/CU grid-limited):
//  * T14 async-STAGE split: next tile's K/V loaded to REGISTERS before QK^T,
//    ds_write'd to LDS after PV -- HBM latency hides under compute instead
//    of draining at the staging barrier (was the exposed 2-phase stall).
//  * T13 defer-max: wave-uniform __any gate skips the O-rescale when the
//    tile max grows < 8 (exact when skipped: alpha == 1).
//  * T5 s_setprio(1) around both MFMA clusters.
// LDS unchanged (58KB, 2 blocks/CU); +48 VGPR for staged tile (stays < 256,
// no occupancy change at 2 waves/SIMD).
// ---------------------------------------------------------------------------
#define FA_N 64

__global__ __launch_bounds__(256, 2) void attn_flash_mfma(const unsigned short* __restrict__ qh,
                                                          const unsigned short* __restrict__ ql,
                                                          const unsigned short* __restrict__ kh,
                                                          const unsigned short* __restrict__ kl,
                                                          const unsigned short* __restrict__ vt,
                                                          unsigned short* __restrict__ out) {
  const int h = blockIdx.y;
  const int kvh = h >> 1;
  const int m0 = blockIdx.x * 64;
  const int tid = threadIdx.x;
  const int lane = tid & 63;
  const int wave = tid >> 6;
  const int rg = wave >> 1;   // row group (32 q-rows)
  const int kg = wave & 1;    // key half (32 of 64 keys)
  const int l15 = lane & 15;
  const int quad = lane >> 4;

  __shared__ char smem[59392];
  unsigned short* Kh = (unsigned short*)(smem);
  unsigned short* Kl = (unsigned short*)(smem + 16384);
  unsigned short* Vt = (unsigned short*)(smem + 32768);
  unsigned short* Pt = (unsigned short*)(smem + 49152) + wave * 1280;  // [32][40]

  // ---- per-thread staging geometry (same swizzle as the DMA path) ----
  const int krow = wave * 16 + (lane >> 4);          // + p*4
  const int kc = (lane & 15);                        // ^ (krow&15) per p
  const int vd = wave * 32 + (lane >> 3);            // + p*8
  const int vc7 = (lane & 7);                        // ^ (d&7) per p

  // ---- Q fragments in registers (A-layout), once ----
  s16x8 qah[2][4], qal[2][4];
#pragma unroll
  for (int rt = 0; rt < 2; ++rt) {
    const int qrow = m0 + rg * 32 + rt * 16 + l15;
#pragma unroll
    for (int ks = 0; ks < 4; ++ks) {
      const size_t off = (size_t)qrow * 2048 + h * HD + ks * 32 + quad * 8;
      qah[rt][ks] = *(const s16x8*)(qh + off);
      qal[rt][ks] = *(const s16x8*)(ql + off);
    }
  }

  f32x4 O[2][8] = {};
  float m_i[2][4], l_i[2][4];
#pragma unroll
  for (int rt = 0; rt < 2; ++rt)
#pragma unroll
    for (int r = 0; r < 4; ++r) { m_i[rt][r] = -1e30f; l_i[rt][r] = 0.f; }

  // ---- prologue: DMA-stage tile 0 directly into LDS ----
#pragma unroll
  for (int p = 0; p < 4; ++p) {
    const int kr = krow + p * 4;
    const size_t ksrc = (size_t)kr * 1024 + kvh * HD + (kc ^ (kr & 15)) * 8;
    const int kdst = (wave * 16 + p * 4) * 128;
    gload16(kh + ksrc, Kh + kdst);
    gload16(kl + ksrc, Kl + kdst);
    const int d = vd + p * 8;
    const size_t vsrc = (size_t)(kvh * HD + d) * 2048 + (vc7 ^ (d & 7)) * 8;
    const int vdst = (wave * 32 + p * 8) * 64;
    gload16(vt + vsrc, Vt + vdst);
  }
  __syncthreads();

  for (int n0 = 0; n0 < S; n0 += FA_N) {
    const int n1 = n0 + FA_N;

    // ---- T14: issue NEXT tile's loads into registers, before compute ----
    s16x8 stKh[4], stKl[4], stV[4];
    if (n1 < S) {
#pragma unroll
      for (int p = 0; p < 4; ++p) {
        const int kr = krow + p * 4;
        const size_t ksrc = (size_t)(n1 + kr) * 1024 + kvh * HD + (kc ^ (kr & 15)) * 8;
        stKh[p] = *(const s16x8*)(kh + ksrc);
        stKl[p] = *(const s16x8*)(kl + ksrc);
        const int d = vd + p * 8;
        const size_t vsrc = (size_t)(kvh * HD + d) * 2048 + n1 + (vc7 ^ (d & 7)) * 8;
        stV[p] = *(const s16x8*)(vt + vsrc);
      }
    }

    // ---- S = Q K^T over this wave's 32-key half, split precision ----
    f32x4 sacc[2][2] = {};
    __builtin_amdgcn_s_setprio(1);
#pragma unroll
    for (int ks = 0; ks < 4; ++ks) {
      s16x8 bh[2], bl[2];
#pragma unroll
      for (int j = 0; j < 2; ++j) {
        const int row = kg * 32 + j * 16 + l15;
        const int cp = ((ks * 4 + quad) ^ l15) * 8;
        const int ro = row * 128 + cp;
        bh[j] = *(const s16x8*)&Kh[ro];
        bl[j] = *(const s16x8*)&Kl[ro];
      }
#pragma unroll
      for (int rt = 0; rt < 2; ++rt)
#pragma unroll
        for (int j = 0; j < 2; ++j) {
          sacc[rt][j] = __builtin_amdgcn_mfma_f32_16x16x32_bf16(qah[rt][ks], bh[j], sacc[rt][j], 0, 0, 0);
          sacc[rt][j] = __builtin_amdgcn_mfma_f32_16x16x32_bf16(qah[rt][ks], bl[j], sacc[rt][j], 0, 0, 0);
          sacc[rt][j] = __builtin_amdgcn_mfma_f32_16x16x32_bf16(qal[rt][ks], bh[j], sacc[rt][j], 0, 0, 0);
        }
    }
    __builtin_amdgcn_s_setprio(0);

    // ---- online softmax; T13 defer-max; l stays per-lane-partial ----
    float mt[2][4];
    float dmax = -1e30f;
#pragma unroll
    for (int rt = 0; rt < 2; ++rt)
#pragma unroll
      for (int r = 0; r < 4; ++r) {
        float m = fmaxf(sacc[rt][0][r], sacc[rt][1][r]);
        m = fmaxf(m, __shfl_xor(m, 1));
        m = fmaxf(m, __shfl_xor(m, 2));
        m = fmaxf(m, __shfl_xor(m, 4));
        m = fmaxf(m, __shfl_xor(m, 8));
        mt[rt][r] = m;
        dmax = fmaxf(dmax, m - m_i[rt][r]);
      }
    if (__any(dmax > 8.f)) {   // wave-uniform: rescale path
#pragma unroll
      for (int rt = 0; rt < 2; ++rt)
#pragma unroll
        for (int r = 0; r < 4; ++r) {
          const float mnew = fmaxf(m_i[rt][r], mt[rt][r]);
          const float alpha = __expf(m_i[rt][r] - mnew);
          m_i[rt][r] = mnew;
          l_i[rt][r] *= alpha;
#pragma unroll
          for (int jd = 0; jd < 8; ++jd) O[rt][jd][r] *= alpha;
        }
    }
#pragma unroll
    for (int rt = 0; rt < 2; ++rt)
#pragma unroll
      for (int r = 0; r < 4; ++r) {
        const float p0 = __expf(sacc[rt][0][r] - m_i[rt][r]);
        const float p1 = __expf(sacc[rt][1][r] - m_i[rt][r]);
        l_i[rt][r] += p0 + p1;
        const int prow = rt * 16 + quad * 4 + r;
        Pt[prow * 40 + l15] = f2bf(p0);
        Pt[prow * 40 + 16 + l15] = f2bf(p1);
      }
    // no barrier: Pt is per-wave private; DS ops within a wave are ordered.

    // ---- O += P V over this wave's 32 keys ----
    s16x8 pa[2];
#pragma unroll
    for (int rt = 0; rt < 2; ++rt)
      pa[rt] = *(const s16x8*)&Pt[(rt * 16 + l15) * 40 + quad * 8];
    __builtin_amdgcn_s_setprio(1);
#pragma unroll
    for (int jd = 0; jd < 8; ++jd) {
      const int d = jd * 16 + l15;
      const int cp = ((kg * 4 + quad) ^ (d & 7)) * 8;
      const s16x8 vb = *(const s16x8*)&Vt[d * 64 + cp];
#pragma unroll
      for (int rt = 0; rt < 2; ++rt)
        O[rt][jd] = __builtin_amdgcn_mfma_f32_16x16x32_bf16(pa[rt], vb, O[rt][jd], 0, 0, 0);
    }
    __builtin_amdgcn_s_setprio(0);

    // ---- T14 write-late: commit staged tile n+1 into LDS ----
    if (n1 < S) {
      __syncthreads();  // all waves done reading tile n's K/V
#pragma unroll
      for (int p = 0; p < 4; ++p) {
        const int kdst = (wave * 16 + p * 4) * 128 + lane * 8;
        *(s16x8*)&Kh[kdst] = stKh[p];
        *(s16x8*)&Kl[kdst] = stKl[p];
        const int vdst = (wave * 32 + p * 8) * 64 + lane * 8;
        *(s16x8*)&Vt[vdst] = stV[p];
      }
      __syncthreads();  // tile n+1 visible to all
    }
  }

  // ---- deferred l reduction (once instead of per tile) ----
#pragma unroll
  for (int rt = 0; rt < 2; ++rt)
#pragma unroll
    for (int r = 0; r < 4; ++r) {
      float ls = l_i[rt][r];
      ls += __shfl_xor(ls, 1);
      ls += __shfl_xor(ls, 2);
      ls += __shfl_xor(ls, 4);
      ls += __shfl_xor(ls, 8);
      l_i[rt][r] = ls;
    }

  // ---- merge the two key-halves per row group, then store ----
  __syncthreads();  // all fragment reads done; reuse LDS
  float* Om = (float*)smem;                 // [2 rg][32 rows][128]
  float* ms = (float*)(smem + 32768);       // [2][32]
  float* ls2 = (float*)(smem + 33024);      // [2][32]

  if (kg == 1) {
#pragma unroll
    for (int rt = 0; rt < 2; ++rt)
#pragma unroll
      for (int r = 0; r < 4; ++r) {
        const int row = rt * 16 + quad * 4 + r;
        if (l15 == 0) {
          ms[rg * 32 + row] = m_i[rt][r];
          ls2[rg * 32 + row] = l_i[rt][r];
        }
#pragma unroll
        for (int jd = 0; jd < 8; ++jd)
          Om[(size_t)(rg * 32 + row) * 128 + jd * 16 + l15] = O[rt][jd][r];
      }
  }
  __syncthreads();
  if (kg == 0) {
#pragma unroll
    for (int rt = 0; rt < 2; ++rt)
#pragma unroll
      for (int r = 0; r < 4; ++r) {
        const int row = rt * 16 + quad * 4 + r;
        const float mB = ms[rg * 32 + row];
        const float lB = ls2[rg * 32 + row];
        const float mS = fmaxf(m_i[rt][r], mB);
        const float aA = __expf(m_i[rt][r] - mS);
        const float aB = __expf(mB - mS);
        const float inv = 1.f / (aA * l_i[rt][r] + aB * lB);
        const int grow = m0 + rg * 32 + row;
#pragma unroll
        for (int jd = 0; jd < 8; ++jd) {
          const float oB = Om[(size_t)(rg * 32 + row) * 128 + jd * 16 + l15];
          out[(size_t)grow * 2048 + h * HD + jd * 16 + l15] =
              f2bf((aA * O[rt][jd][r] + aB * oB) * inv);
        }
      }
  }
}

// ---------------------------------------------------------------------------
extern "C" void kernel_launch(void* const* d_in, const int* in_sizes, int n_in,
                              void* d_out, int out_size, void* d_ws, size_t ws_size,
                              hipStream_t stream) {
  const float* hidden = (const float*)d_in[0];  // [S][HID]
  const float* cosb   = (const float*)d_in[1];  // [S][HD]
  const float* sinb   = (const float*)d_in[2];  // [S][HD]
  const float* wq     = (const float*)d_in[3];  // [HID][2048]
  const float* wk     = (const float*)d_in[4];  // [HID][1024]
  const float* wv     = (const float*)d_in[5];  // [HID][1024]
  const float* wo     = (const float*)d_in[6];  // [2048][HID]
  float* out = (float*)d_out;                   // [S][HID]

  // Workspace map (72 MB, regions reused once dead):
  char* w = (char*)d_ws;
  float* qk_buf           = (float*)(w);                          //  0-24 MB fp32 [S][3072]
  unsigned short* wqkT_hi = (unsigned short*)(w + (24u << 20));   // 24-36 (dead after QK gemm)
  unsigned short* wqkT_lo = (unsigned short*)(w + (36u << 20));   // 36-48 (dead after QK gemm)
  unsigned short* hid_hi  = (unsigned short*)(w + (48u << 20));   // 48-56 (dead after V gemm)
  unsigned short* hid_lo  = (unsigned short*)(w + (56u << 20));   // 56-64 (dead after QK gemm)
  unsigned short* vt_b    = (unsigned short*)(w + (64u << 20));   // 64-68 V^T bf16 [1024][2048]
  unsigned short* wvT     = (unsigned short*)(w + (68u << 20));   // 68-72
  // reuse after QK gemm:
  unsigned short* q_hi    = (unsigned short*)(w + (24u << 20));   // 24-32 [S][2048]
  unsigned short* q_lo    = (unsigned short*)(w + (32u << 20));   // 32-40
  unsigned short* k_hi    = (unsigned short*)(w + (40u << 20));   // 40-44 [S][1024]
  unsigned short* k_lo    = (unsigned short*)(w + (44u << 20));   // 44-48
  // reuse after V gemm:
  unsigned short* woT     = (unsigned short*)(w + (48u << 20));   // 48-56 [2048][2048]
  unsigned short* a_b     = (unsigned short*)(w + (56u << 20));   // 56-64 [S][2048]

  dim3 blk(256);

  // prologue
  f32_to_bf16_split<<<dim3((S * HID / 4 + 255) / 256), blk, 0, stream>>>(hidden, hid_hi, hid_lo, S * HID / 4);
  transpose_to_bf16_split<<<dim3(32, 32), blk, 0, stream>>>(wq, wqkT_hi, wqkT_lo, HID, 2048);
  transpose_to_bf16_split<<<dim3(16, 32), blk, 0, stream>>>(wk, wqkT_hi + (size_t)2048 * 2048,
                                                            wqkT_lo + (size_t)2048 * 2048, HID, 1024);
  transpose_to_bf16<<<dim3(16, 32), blk, 0, stream>>>(wv, wvT, 2048, 1024);

  // QK projection (split precision) -> fp32 [S][3072]
  gemm_split_bt<<<dim3(3072 / BN, S / BM), blk, 0, stream>>>(hid_hi, hid_lo, wqkT_hi, wqkT_lo,
                                                             qk_buf, S, 3072, HID, 3072);

  // V projection -> transposed bf16 [1024][2048]; 128x64 tile, 256 blocks
  gemm_bf16_bt64<1, unsigned short><<<dim3(1024 / 64, S / BM), blk, 0, stream>>>(
      hid_hi, wvT, vt_b, S, 1024, HID, 2048);

  // wo transpose into dead hid_hi region (after V gemm in stream order)
  transpose_to_bf16<<<dim3(32, 32), blk, 0, stream>>>(wo, woT, 2048, HID);

  // RMSNorm + RoPE -> split bf16 q/k (q pre-scaled); wave-per-row
  rmsnorm_rope_split<<<dim3(S, 6), blk, 0, stream>>>(qk_buf, cosb, sinb, q_hi, q_lo, k_hi, k_lo);

  // MFMA flash attention -> bf16 [S][2048]
  attn_flash_mfma<<<dim3(S / 64, NH), blk, 0, stream>>>(q_hi, q_lo, k_hi, k_lo, vt_b, a_b);

  // output projection -> fp32 out; 128x64 tile, 512 blocks
  gemm_bf16_bt64<0, float><<<dim3(HID / 64, S / BM), blk, 0, stream>>>(
      a_b, woT, out, S, HID, 2048, HID);
}

// Round 2
// 420.813 us; speedup vs baseline: 1.2500x; 1.2500x over previous
//
#include <hip/hip_runtime.h>
#include <hip/hip_bf16.h>
#include <math.h>

// Problem constants
#define S 2048
#define HID 2048
#define NH 16
#define KVH 8
#define HD 128
#define EPS 1e-6f
#define QK_SCALE 11.313708498984760390f  // 1/SCALING = sqrt(128)

typedef __attribute__((ext_vector_type(8))) short s16x8;
typedef __attribute__((ext_vector_type(4))) float f32x4;

__device__ __forceinline__ unsigned short f2bf(float f) {
  __hip_bfloat16 h = __float2bfloat16(f);
  return *(unsigned short*)&h;
}
__device__ __forceinline__ float bf2f(unsigned short u) {
  unsigned int x = ((unsigned int)u) << 16;
  return __builtin_bit_cast(float, x);
}

__device__ __forceinline__ void gload16(const void* g, void* l) {
  __builtin_amdgcn_global_load_lds(
      (const __attribute__((address_space(1))) void*)g,
      (__attribute__((address_space(3))) void*)l, 16, 0, 0);
}

// ---------------------------------------------------------------------------
// fp32 -> split bf16 (hi + lo) elementwise.
// ---------------------------------------------------------------------------
__global__ __launch_bounds__(256) void f32_to_bf16_split(const float* __restrict__ in,
                                                         unsigned short* __restrict__ hi,
                                                         unsigned short* __restrict__ lo,
                                                         int n4) {
  const int i = blockIdx.x * 256 + threadIdx.x;
  if (i < n4) {
    const float4 v = *(const float4*)(in + (size_t)i * 4);
    ushort4 h, l;
    h.x = f2bf(v.x); l.x = f2bf(v.x - bf2f(h.x));
    h.y = f2bf(v.y); l.y = f2bf(v.y - bf2f(h.y));
    h.z = f2bf(v.z); l.z = f2bf(v.z - bf2f(h.z));
    h.w = f2bf(v.w); l.w = f2bf(v.w - bf2f(h.w));
    *(ushort4*)(hi + (size_t)i * 4) = h;
    *(ushort4*)(lo + (size_t)i * 4) = l;
  }
}

// ---------------------------------------------------------------------------
// Transpose fp32 [K][N] -> bf16 [N][K], plain.
// ---------------------------------------------------------------------------
__global__ __launch_bounds__(256) void transpose_to_bf16(const float* __restrict__ in,
                                                         unsigned short* __restrict__ out,
                                                         int K, int N) {
  __shared__ float t[64][65];
  const int n0 = blockIdx.x * 64;
  const int k0 = blockIdx.y * 64;
  const int tid = threadIdx.x;

  for (int idx = tid; idx < 64 * 16; idx += 256) {
    const int r = idx >> 4;
    const int c4 = (idx & 15) * 4;
    const float4 v = *(const float4*)(in + (size_t)(k0 + r) * N + n0 + c4);
    t[r][c4 + 0] = v.x; t[r][c4 + 1] = v.y; t[r][c4 + 2] = v.z; t[r][c4 + 3] = v.w;
  }
  __syncthreads();
  for (int idx = tid; idx < 64 * 16; idx += 256) {
    const int a = idx >> 4;
    const int b4 = (idx & 15) * 4;
    ushort4 u;
    u.x = f2bf(t[b4 + 0][a]); u.y = f2bf(t[b4 + 1][a]);
    u.z = f2bf(t[b4 + 2][a]); u.w = f2bf(t[b4 + 3][a]);
    *(ushort4*)(out + (size_t)(n0 + a) * K + k0 + b4) = u;
  }
}

// ---------------------------------------------------------------------------
// Transpose fp32 [K][N] -> split bf16 hi/lo [N][K].
// ---------------------------------------------------------------------------
__global__ __launch_bounds__(256) void transpose_to_bf16_split(const float* __restrict__ in,
                                                               unsigned short* __restrict__ ohi,
                                                               unsigned short* __restrict__ olo,
                                                               int K, int N) {
  __shared__ float t[64][65];
  const int n0 = blockIdx.x * 64;
  const int k0 = blockIdx.y * 64;
  const int tid = threadIdx.x;

  for (int idx = tid; idx < 64 * 16; idx += 256) {
    const int r = idx >> 4;
    const int c4 = (idx & 15) * 4;
    const float4 v = *(const float4*)(in + (size_t)(k0 + r) * N + n0 + c4);
    t[r][c4 + 0] = v.x; t[r][c4 + 1] = v.y; t[r][c4 + 2] = v.z; t[r][c4 + 3] = v.w;
  }
  __syncthreads();
  for (int idx = tid; idx < 64 * 16; idx += 256) {
    const int a = idx >> 4;
    const int b4 = (idx & 15) * 4;
    ushort4 h, l;
#pragma unroll
    for (int q = 0; q < 4; ++q) {
      const float v = t[b4 + q][a];
      const unsigned short hu = f2bf(v);
      const unsigned short lu = f2bf(v - bf2f(hu));
      ((unsigned short*)&h)[q] = hu;
      ((unsigned short*)&l)[q] = lu;
    }
    *(ushort4*)(ohi + (size_t)(n0 + a) * K + k0 + b4) = h;
    *(ushort4*)(olo + (size_t)(n0 + a) * K + k0 + b4) = l;
  }
}

// ---------------------------------------------------------------------------
// Plain bf16 MFMA GEMM (m97 structure): C[M][ldc] = A[M][K] * Bt[N][K]^T.
// 128x128 tile.
// ---------------------------------------------------------------------------
#define BM 128
#define BN 128
#define BK 32

template <typename OT>
__global__ __launch_bounds__(256) void gemm_bf16_bt(const unsigned short* __restrict__ A,
                                                    const unsigned short* __restrict__ Bt,
                                                    OT* __restrict__ C,
                                                    int M, int N, int K, int ldc) {
  __shared__ unsigned short As[BM * BK];
  __shared__ unsigned short Bs[BN * BK];

  const int tid = threadIdx.x;
  const int lane = tid & 63;
  const int wave = tid >> 6;
  const int m0 = blockIdx.y * BM;
  const int n0 = blockIdx.x * BN;

  const int qm = (wave >> 1) * 64;
  const int qn = (wave & 1) * 64;
  const int l15 = lane & 15;
  const int quad = lane >> 4;

  const int st_row = lane >> 2;
  const int st_col = (lane & 3) * 8;

  f32x4 acc[4][4] = {};

  for (int k0 = 0; k0 < K; k0 += BK) {
#pragma unroll
    for (int p = 0; p < 2; ++p) {
      const int rb = p * 64 + wave * 16;
      gload16(A + (size_t)(m0 + rb + st_row) * K + k0 + st_col, &As[rb * BK]);
      gload16(Bt + (size_t)(n0 + rb + st_row) * K + k0 + st_col, &Bs[rb * BK]);
    }
    __syncthreads();

    s16x8 a[4], b[4];
#pragma unroll
    for (int i = 0; i < 4; ++i)
      a[i] = *(const s16x8*)&As[(qm + i * 16 + l15) * BK + quad * 8];
#pragma unroll
    for (int j = 0; j < 4; ++j)
      b[j] = *(const s16x8*)&Bs[(qn + j * 16 + l15) * BK + quad * 8];
#pragma unroll
    for (int i = 0; i < 4; ++i)
#pragma unroll
      for (int j = 0; j < 4; ++j)
        acc[i][j] = __builtin_amdgcn_mfma_f32_16x16x32_bf16(a[i], b[j], acc[i][j], 0, 0, 0);
    __syncthreads();
  }

#pragma unroll
  for (int i = 0; i < 4; ++i) {
    const int row_base = m0 + qm + i * 16 + quad * 4;
#pragma unroll
    for (int j = 0; j < 4; ++j) {
      const int col = n0 + qn + j * 16 + l15;
#pragma unroll
      for (int r = 0; r < 4; ++r) {
        if constexpr (sizeof(OT) == 2)
          C[(size_t)(row_base + r) * ldc + col] = (OT)f2bf(acc[i][j][r]);
        else
          C[(size_t)(row_base + r) * ldc + col] = acc[i][j][r];
      }
    }
  }
}

// ---------------------------------------------------------------------------
// 128x64-tile bf16 MFMA GEMM for grid-starved shapes (V proj, wo proj).
// MODE 0: float C store. MODE 1: transposed bf16 store Ct[n][ldct]+m.
// ---------------------------------------------------------------------------
template <int MODE, typename OT>
__global__ __launch_bounds__(256) void gemm_bf16_bt64(const unsigned short* __restrict__ A,
                                                      const unsigned short* __restrict__ Bt,
                                                      OT* __restrict__ C,
                                                      int M, int N, int K, int ldc) {
  __shared__ unsigned short As[BM * BK];
  __shared__ unsigned short Bs[64 * BK];

  const int tid = threadIdx.x;
  const int lane = tid & 63;
  const int wave = tid >> 6;
  const int m0 = blockIdx.y * BM;
  const int n0 = blockIdx.x * 64;

  const int qm = (wave >> 1) * 64;
  const int qn = (wave & 1) * 32;
  const int l15 = lane & 15;
  const int quad = lane >> 4;

  const int st_row = lane >> 2;
  const int st_col = (lane & 3) * 8;

  f32x4 acc[4][2] = {};

  for (int k0 = 0; k0 < K; k0 += BK) {
#pragma unroll
    for (int p = 0; p < 2; ++p) {
      const int rb = p * 64 + wave * 16;
      gload16(A + (size_t)(m0 + rb + st_row) * K + k0 + st_col, &As[rb * BK]);
    }
    {
      const int rb = wave * 16;
      gload16(Bt + (size_t)(n0 + rb + st_row) * K + k0 + st_col, &Bs[rb * BK]);
    }
    __syncthreads();

    s16x8 a[4], b[2];
#pragma unroll
    for (int i = 0; i < 4; ++i)
      a[i] = *(const s16x8*)&As[(qm + i * 16 + l15) * BK + quad * 8];
#pragma unroll
    for (int j = 0; j < 2; ++j)
      b[j] = *(const s16x8*)&Bs[(qn + j * 16 + l15) * BK + quad * 8];
#pragma unroll
    for (int i = 0; i < 4; ++i)
#pragma unroll
      for (int j = 0; j < 2; ++j)
        acc[i][j] = __builtin_amdgcn_mfma_f32_16x16x32_bf16(a[i], b[j], acc[i][j], 0, 0, 0);
    __syncthreads();
  }

#pragma unroll
  for (int i = 0; i < 4; ++i) {
    const int row_base = m0 + qm + i * 16 + quad * 4;
#pragma unroll
    for (int j = 0; j < 2; ++j) {
      const int col = n0 + qn + j * 16 + l15;
      if constexpr (MODE == 0) {
#pragma unroll
        for (int r = 0; r < 4; ++r)
          C[(size_t)(row_base + r) * ldc + col] = acc[i][j][r];
      } else {
        ushort4 u;
        u.x = f2bf(acc[i][j][0]); u.y = f2bf(acc[i][j][1]);
        u.z = f2bf(acc[i][j][2]); u.w = f2bf(acc[i][j][3]);
        *(ushort4*)((unsigned short*)C + (size_t)col * ldc + row_base) = u;
      }
    }
  }
}

// ---------------------------------------------------------------------------
// Split-precision bf16 MFMA GEMM: C = (Ahi+Alo) * (Bhi+Blo)^T, dropping lo*lo.
// ---------------------------------------------------------------------------
__global__ __launch_bounds__(256) void gemm_split_bt(const unsigned short* __restrict__ Ahi,
                                                     const unsigned short* __restrict__ Alo,
                                                     const unsigned short* __restrict__ Bhi,
                                                     const unsigned short* __restrict__ Blo,
                                                     float* __restrict__ C,
                                                     int M, int N, int K, int ldc) {
  __shared__ unsigned short AsH[BM * BK];
  __shared__ unsigned short AsL[BM * BK];
  __shared__ unsigned short BsH[BN * BK];
  __shared__ unsigned short BsL[BN * BK];

  const int tid = threadIdx.x;
  const int lane = tid & 63;
  const int wave = tid >> 6;
  const int m0 = blockIdx.y * BM;
  const int n0 = blockIdx.x * BN;

  const int qm = (wave >> 1) * 64;
  const int qn = (wave & 1) * 64;
  const int l15 = lane & 15;
  const int quad = lane >> 4;

  const int st_row = lane >> 2;
  const int st_col = (lane & 3) * 8;

  f32x4 acc[4][4] = {};

  for (int k0 = 0; k0 < K; k0 += BK) {
#pragma unroll
    for (int p = 0; p < 2; ++p) {
      const int rb = p * 64 + wave * 16;
      const size_t aoff = (size_t)(m0 + rb + st_row) * K + k0 + st_col;
      const size_t boff = (size_t)(n0 + rb + st_row) * K + k0 + st_col;
      gload16(Ahi + aoff, &AsH[rb * BK]);
      gload16(Alo + aoff, &AsL[rb * BK]);
      gload16(Bhi + boff, &BsH[rb * BK]);
      gload16(Blo + boff, &BsL[rb * BK]);
    }
    __syncthreads();

    s16x8 ah[4], al[4], bh[4], bl[4];
#pragma unroll
    for (int i = 0; i < 4; ++i) {
      const int ro = (qm + i * 16 + l15) * BK + quad * 8;
      ah[i] = *(const s16x8*)&AsH[ro];
      al[i] = *(const s16x8*)&AsL[ro];
    }
#pragma unroll
    for (int j = 0; j < 4; ++j) {
      const int ro = (qn + j * 16 + l15) * BK + quad * 8;
      bh[j] = *(const s16x8*)&BsH[ro];
      bl[j] = *(const s16x8*)&BsL[ro];
    }
#pragma unroll
    for (int i = 0; i < 4; ++i)
#pragma unroll
      for (int j = 0; j < 4; ++j) {
        acc[i][j] = __builtin_amdgcn_mfma_f32_16x16x32_bf16(ah[i], bh[j], acc[i][j], 0, 0, 0);
        acc[i][j] = __builtin_amdgcn_mfma_f32_16x16x32_bf16(ah[i], bl[j], acc[i][j], 0, 0, 0);
        acc[i][j] = __builtin_amdgcn_mfma_f32_16x16x32_bf16(al[i], bh[j], acc[i][j], 0, 0, 0);
      }
    __syncthreads();
  }

#pragma unroll
  for (int i = 0; i < 4; ++i) {
    const int row_base = m0 + qm + i * 16 + quad * 4;
#pragma unroll
    for (int j = 0; j < 4; ++j) {
      const int col = n0 + qn + j * 16 + l15;
#pragma unroll
      for (int r = 0; r < 4; ++r)
        C[(size_t)(row_base + r) * ldc + col] = acc[i][j][r];
    }
  }
}

// ---------------------------------------------------------------------------
// Fused RMSNorm + RoPE, wave-per-row shfl version (no LDS, no barriers).
// ---------------------------------------------------------------------------
__global__ __launch_bounds__(256) void rmsnorm_rope_split(const float* __restrict__ qk,
                                                          const float* __restrict__ cosb,
                                                          const float* __restrict__ sinb,
                                                          unsigned short* __restrict__ qh,
                                                          unsigned short* __restrict__ ql,
                                                          unsigned short* __restrict__ kh,
                                                          unsigned short* __restrict__ kl) {
  const int s = blockIdx.x;
  const int wave = threadIdx.x >> 6;
  const int lane = threadIdx.x & 63;
  const int hh = blockIdx.y * 4 + wave;
  const bool is_q = (hh < 16);
  const int col = is_q ? hh * HD : 2048 + (hh - 16) * HD;

  const float* row = qk + (size_t)s * 3072 + col;
  const float x1 = row[lane];
  const float x2 = row[lane + 64];

  float ss = x1 * x1 + x2 * x2;
  ss += __shfl_xor(ss, 1);
  ss += __shfl_xor(ss, 2);
  ss += __shfl_xor(ss, 4);
  ss += __shfl_xor(ss, 8);
  ss += __shfl_xor(ss, 16);
  ss += __shfl_xor(ss, 32);
  const float r = rsqrtf(ss / 128.f + EPS);

  const float c = cosb[(size_t)s * HD + lane];
  const float sn = sinb[(size_t)s * HD + lane];
  float o1 = x1 * r * c - x2 * r * sn;   // d = lane
  float o2 = x2 * r * c + x1 * r * sn;   // d = lane + 64
  if (is_q) { o1 *= QK_SCALE; o2 *= QK_SCALE; }

  const unsigned short h1 = f2bf(o1), l1 = f2bf(o1 - bf2f(h1));
  const unsigned short h2 = f2bf(o2), l2 = f2bf(o2 - bf2f(h2));
  if (is_q) {
    const size_t base = (size_t)s * 2048 + hh * HD + lane;
    qh[base] = h1; ql[base] = l1;
    qh[base + 64] = h2; ql[base + 64] = l2;
  } else {
    const size_t base = (size_t)s * 1024 + (hh - 16) * HD + lane;
    kh[base] = h1; kl[base] = l1;
    kh[base + 64] = h2; kl[base + 64] = l2;
  }
}

// ---------------------------------------------------------------------------
// Flash attention, MFMA, DOUBLE-BUFFERED DMA pipeline.
// Post-mortem R1: register prefetch was defeated by the compiler (VGPR stayed
// 128, WRITE_SIZE 3x = scratch). This version keeps global_load_lds DMA but
// adds a second LDS K/V buffer: each tile's loads are issued right AFTER the
// barrier and drained by the NEXT tile's __syncthreads (vmcnt(0) is then a
// no-op since a full compute phase has passed). One barrier per tile.
//  - 512 threads / 8 waves (4 row groups x 2 key halves, 16 q-rows per wave)
//    so 1 block/CU keeps 2 waves/SIMD (same occupancy as before).
//  - LDS 108544 B: 2 x (Kh 16K | Kl 16K | Vt 16K) + Pt 10K. Large static LDS
//    is proven on gfx950 (128 KiB 8-phase template).
//  - T13 defer-max and T5 setprio kept.
// ---------------------------------------------------------------------------
#define FA_N 64
#define FA_NT (S / FA_N)

__global__ __launch_bounds__(512, 2) void attn_flash_mfma(const unsigned short* __restrict__ qh,
                                                          const unsigned short* __restrict__ ql,
                                                          const unsigned short* __restrict__ kh,
                                                          const unsigned short* __restrict__ kl,
                                                          const unsigned short* __restrict__ vt,
                                                          unsigned short* __restrict__ out) {
  const int h = blockIdx.y;
  const int kvh = h >> 1;
  const int m0 = blockIdx.x * 64;
  const int tid = threadIdx.x;
  const int lane = tid & 63;
  const int wave = tid >> 6;   // 0..7
  const int rg = wave >> 1;    // row group (16 q-rows)
  const int kg = wave & 1;     // key half (32 of 64 keys)
  const int l15 = lane & 15;
  const int quad = lane >> 4;

  __shared__ char smem[108544];
  // buffer b (b=0,1): Kh @ b*49152, Kl @ +16384B, Vt @ +32768B
  unsigned short* Pt = (unsigned short*)(smem + 98304) + wave * 640;  // [16][40]

  // ---- DMA staging: each wave stages 8 K-rows (hi+lo) and 16 V-rows ----
  auto STAGE = [&](int nt, int buf) {
    unsigned short* KhB = (unsigned short*)(smem + buf * 49152);
    unsigned short* KlB = KhB + 8192;
    unsigned short* VtB = KhB + 16384;
#pragma unroll
    for (int p = 0; p < 2; ++p) {
      const int kr = wave * 8 + p * 4 + (lane >> 4);
      const size_t ksrc = (size_t)(nt + kr) * 1024 + kvh * HD + ((lane & 15) ^ (kr & 15)) * 8;
      gload16(kh + ksrc, KhB + (wave * 8 + p * 4) * 128);
      gload16(kl + ksrc, KlB + (wave * 8 + p * 4) * 128);
      const int d = wave * 16 + p * 8 + (lane >> 3);
      const size_t vsrc = (size_t)(kvh * HD + d) * 2048 + nt + ((lane & 7) ^ (d & 7)) * 8;
      gload16(vt + vsrc, VtB + (wave * 16 + p * 8) * 64);
    }
  };

  // ---- Q fragments in registers (A-layout), once ----
  s16x8 qah[4], qal[4];
  {
    const int qrow = m0 + rg * 16 + l15;
#pragma unroll
    for (int ks = 0; ks < 4; ++ks) {
      const size_t off = (size_t)qrow * 2048 + h * HD + ks * 32 + quad * 8;
      qah[ks] = *(const s16x8*)(qh + off);
      qal[ks] = *(const s16x8*)(ql + off);
    }
  }

  f32x4 O[8] = {};
  float m_i[4], l_i[4];
#pragma unroll
  for (int r = 0; r < 4; ++r) { m_i[r] = -1e30f; l_i[r] = 0.f; }

  // ---- prologue: stage tile 0 into buffer 0 ----
  STAGE(0, 0);

  for (int t = 0; t < FA_NT; ++t) {
    unsigned short* Kh = (unsigned short*)(smem + (t & 1) * 49152);
    unsigned short* Kl = Kh + 8192;
    unsigned short* Vt = Kh + 16384;

    // drains own tile-t DMA (issued a full compute phase ago) + publishes all
    __syncthreads();
    // issue tile t+1 into the other buffer (everyone is past compute t-1)
    if (t + 1 < FA_NT) STAGE((t + 1) * FA_N, (t + 1) & 1);

    // ---- S = Q K^T over this wave's 32-key half, split precision ----
    f32x4 sacc[2] = {};
    __builtin_amdgcn_s_setprio(1);
#pragma unroll
    for (int ks = 0; ks < 4; ++ks) {
      s16x8 bh[2], bl[2];
#pragma unroll
      for (int j = 0; j < 2; ++j) {
        const int row = kg * 32 + j * 16 + l15;
        const int ro = row * 128 + (((ks * 4 + quad) ^ l15) * 8);
        bh[j] = *(const s16x8*)&Kh[ro];
        bl[j] = *(const s16x8*)&Kl[ro];
      }
#pragma unroll
      for (int j = 0; j < 2; ++j) {
        sacc[j] = __builtin_amdgcn_mfma_f32_16x16x32_bf16(qah[ks], bh[j], sacc[j], 0, 0, 0);
        sacc[j] = __builtin_amdgcn_mfma_f32_16x16x32_bf16(qah[ks], bl[j], sacc[j], 0, 0, 0);
        sacc[j] = __builtin_amdgcn_mfma_f32_16x16x32_bf16(qal[ks], bh[j], sacc[j], 0, 0, 0);
      }
    }
    __builtin_amdgcn_s_setprio(0);

    // ---- online softmax; T13 defer-max; l stays per-lane-partial ----
    float mt[4];
    float dmax = -1e30f;
#pragma unroll
    for (int r = 0; r < 4; ++r) {
      float m = fmaxf(sacc[0][r], sacc[1][r]);
      m = fmaxf(m, __shfl_xor(m, 1));
      m = fmaxf(m, __shfl_xor(m, 2));
      m = fmaxf(m, __shfl_xor(m, 4));
      m = fmaxf(m, __shfl_xor(m, 8));
      mt[r] = m;
      dmax = fmaxf(dmax, m - m_i[r]);
    }
    if (__any(dmax > 8.f)) {   // wave-uniform rescale path
#pragma unroll
      for (int r = 0; r < 4; ++r) {
        const float mnew = fmaxf(m_i[r], mt[r]);
        const float alpha = __expf(m_i[r] - mnew);
        m_i[r] = mnew;
        l_i[r] *= alpha;
#pragma unroll
        for (int jd = 0; jd < 8; ++jd) O[jd][r] *= alpha;
      }
    }
#pragma unroll
    for (int r = 0; r < 4; ++r) {
      const float p0 = __expf(sacc[0][r] - m_i[r]);
      const float p1 = __expf(sacc[1][r] - m_i[r]);
      l_i[r] += p0 + p1;
      const int prow = quad * 4 + r;
      Pt[prow * 40 + l15] = f2bf(p0);
      Pt[prow * 40 + 16 + l15] = f2bf(p1);
    }
    // no barrier: Pt is per-wave private; DS ops within a wave are ordered.

    // ---- O += P V over this wave's 32 keys ----
    const s16x8 pa = *(const s16x8*)&Pt[l15 * 40 + quad * 8];
    __builtin_amdgcn_s_setprio(1);
#pragma unroll
    for (int jd = 0; jd < 8; ++jd) {
      const int d = jd * 16 + l15;
      const int cp = ((kg * 4 + quad) ^ (d & 7)) * 8;
      const s16x8 vb = *(const s16x8*)&Vt[d * 64 + cp];
      O[jd] = __builtin_amdgcn_mfma_f32_16x16x32_bf16(pa, vb, O[jd], 0, 0, 0);
    }
    __builtin_amdgcn_s_setprio(0);
  }

  // ---- deferred l reduction (once instead of per tile) ----
#pragma unroll
  for (int r = 0; r < 4; ++r) {
    float ls = l_i[r];
    ls += __shfl_xor(ls, 1);
    ls += __shfl_xor(ls, 2);
    ls += __shfl_xor(ls, 4);
    ls += __shfl_xor(ls, 8);
    l_i[r] = ls;
  }

  // ---- merge the two key-halves per row group, then store ----
  __syncthreads();  // all fragment reads done; reuse LDS
  float* Om = (float*)smem;                 // [64 rows][128]
  float* ms = (float*)(smem + 32768);       // [64]
  float* ls2 = (float*)(smem + 33024);      // [64]

  if (kg == 1) {
#pragma unroll
    for (int r = 0; r < 4; ++r) {
      const int row = rg * 16 + quad * 4 + r;
      if (l15 == 0) { ms[row] = m_i[r]; ls2[row] = l_i[r]; }
#pragma unroll
      for (int jd = 0; jd < 8; ++jd)
        Om[(size_t)row * 128 + jd * 16 + l15] = O[jd][r];
    }
  }
  __syncthreads();
  if (kg == 0) {
#pragma unroll
    for (int r = 0; r < 4; ++r) {
      const int row = rg * 16 + quad * 4 + r;
      const float mB = ms[row];
      const float lB = ls2[row];
      const float mS = fmaxf(m_i[r], mB);
      const float aA = __expf(m_i[r] - mS);
      const float aB = __expf(mB - mS);
      const float inv = 1.f / (aA * l_i[r] + aB * lB);
      const int grow = m0 + row;
#pragma unroll
      for (int jd = 0; jd < 8; ++jd) {
        const float oB = Om[(size_t)row * 128 + jd * 16 + l15];
        out[(size_t)grow * 2048 + h * HD + jd * 16 + l15] =
            f2bf((aA * O[jd][r] + aB * oB) * inv);
      }
    }
  }
}

// ---------------------------------------------------------------------------
extern "C" void kernel_launch(void* const* d_in, const int* in_sizes, int n_in,
                              void* d_out, int out_size, void* d_ws, size_t ws_size,
                              hipStream_t stream) {
  const float* hidden = (const float*)d_in[0];  // [S][HID]
  const float* cosb   = (const float*)d_in[1];  // [S][HD]
  const float* sinb   = (const float*)d_in[2];  // [S][HD]
  const float* wq     = (const float*)d_in[3];  // [HID][2048]
  const float* wk     = (const float*)d_in[4];  // [HID][1024]
  const float* wv     = (const float*)d_in[5];  // [HID][1024]
  const float* wo     = (const float*)d_in[6];  // [2048][HID]
  float* out = (float*)d_out;                   // [S][HID]

  // Workspace map (72 MB, regions reused once dead):
  char* w = (char*)d_ws;
  float* qk_buf           = (float*)(w);                          //  0-24 MB fp32 [S][3072]
  unsigned short* wqkT_hi = (unsigned short*)(w + (24u << 20));   // 24-36 (dead after QK gemm)
  unsigned short* wqkT_lo = (unsigned short*)(w + (36u << 20));   // 36-48 (dead after QK gemm)
  unsigned short* hid_hi  = (unsigned short*)(w + (48u << 20));   // 48-56 (dead after V gemm)
  unsigned short* hid_lo  = (unsigned short*)(w + (56u << 20));   // 56-64 (dead after QK gemm)
  unsigned short* vt_b    = (unsigned short*)(w + (64u << 20));   // 64-68 V^T bf16 [1024][2048]
  unsigned short* wvT     = (unsigned short*)(w + (68u << 20));   // 68-72
  // reuse after QK gemm:
  unsigned short* q_hi    = (unsigned short*)(w + (24u << 20));   // 24-32 [S][2048]
  unsigned short* q_lo    = (unsigned short*)(w + (32u << 20));   // 32-40
  unsigned short* k_hi    = (unsigned short*)(w + (40u << 20));   // 40-44 [S][1024]
  unsigned short* k_lo    = (unsigned short*)(w + (44u << 20));   // 44-48
  // reuse after V gemm:
  unsigned short* woT     = (unsigned short*)(w + (48u << 20));   // 48-56 [2048][2048]
  unsigned short* a_b     = (unsigned short*)(w + (56u << 20));   // 56-64 [S][2048]

  dim3 blk(256);

  // prologue
  f32_to_bf16_split<<<dim3((S * HID / 4 + 255) / 256), blk, 0, stream>>>(hidden, hid_hi, hid_lo, S * HID / 4);
  transpose_to_bf16_split<<<dim3(32, 32), blk, 0, stream>>>(wq, wqkT_hi, wqkT_lo, HID, 2048);
  transpose_to_bf16_split<<<dim3(16, 32), blk, 0, stream>>>(wk, wqkT_hi + (size_t)2048 * 2048,
                                                            wqkT_lo + (size_t)2048 * 2048, HID, 1024);
  transpose_to_bf16<<<dim3(16, 32), blk, 0, stream>>>(wv, wvT, 2048, 1024);

  // QK projection (split precision) -> fp32 [S][3072]
  gemm_split_bt<<<dim3(3072 / BN, S / BM), blk, 0, stream>>>(hid_hi, hid_lo, wqkT_hi, wqkT_lo,
                                                             qk_buf, S, 3072, HID, 3072);

  // V projection -> transposed bf16 [1024][2048]; 128x64 tile, 256 blocks
  gemm_bf16_bt64<1, unsigned short><<<dim3(1024 / 64, S / BM), blk, 0, stream>>>(
      hid_hi, wvT, vt_b, S, 1024, HID, 2048);

  // wo transpose into dead hid_hi region (after V gemm in stream order)
  transpose_to_bf16<<<dim3(32, 32), blk, 0, stream>>>(wo, woT, 2048, HID);

  // RMSNorm + RoPE -> split bf16 q/k (q pre-scaled); wave-per-row
  rmsnorm_rope_split<<<dim3(S, 6), blk, 0, stream>>>(qk_buf, cosb, sinb, q_hi, q_lo, k_hi, k_lo);

  // MFMA flash attention (512 threads / 8 waves, dbuf pipeline) -> bf16 [S][2048]
  attn_flash_mfma<<<dim3(S / 64, NH), dim3(512), 0, stream>>>(q_hi, q_lo, k_hi, k_lo, vt_b, a_b);

  // output projection -> fp32 out; 128x64 tile, 512 blocks
  gemm_bf16_bt64<0, float><<<dim3(HID / 64, S / BM), blk, 0, stream>>>(
      a_b, woT, out, S, HID, 2048, HID);
}

// Round 3
// 399.056 us; speedup vs baseline: 1.3181x; 1.0545x over previous
//
#include <hip/hip_runtime.h>
#include <hip/hip_bf16.h>
#include <math.h>

// Problem constants
#define S 2048
#define HID 2048
#define NH 16
#define KVH 8
#define HD 128
#define EPS 1e-6f
#define QK_SCALE 11.313708498984760390f  // 1/SCALING = sqrt(128)

typedef __attribute__((ext_vector_type(8))) short s16x8;
typedef __attribute__((ext_vector_type(4))) float f32x4;

__device__ __forceinline__ unsigned short f2bf(float f) {
  __hip_bfloat16 h = __float2bfloat16(f);
  return *(unsigned short*)&h;
}
__device__ __forceinline__ float bf2f(unsigned short u) {
  unsigned int x = ((unsigned int)u) << 16;
  return __builtin_bit_cast(float, x);
}

__device__ __forceinline__ void gload16(const void* g, void* l) {
  __builtin_amdgcn_global_load_lds(
      (const __attribute__((address_space(1))) void*)g,
      (__attribute__((address_space(3))) void*)l, 16, 0, 0);
}

// ---------------------------------------------------------------------------
// fp32 -> split bf16 (hi + lo) elementwise.
// ---------------------------------------------------------------------------
__global__ __launch_bounds__(256) void f32_to_bf16_split(const float* __restrict__ in,
                                                         unsigned short* __restrict__ hi,
                                                         unsigned short* __restrict__ lo,
                                                         int n4) {
  const int i = blockIdx.x * 256 + threadIdx.x;
  if (i < n4) {
    const float4 v = *(const float4*)(in + (size_t)i * 4);
    ushort4 h, l;
    h.x = f2bf(v.x); l.x = f2bf(v.x - bf2f(h.x));
    h.y = f2bf(v.y); l.y = f2bf(v.y - bf2f(h.y));
    h.z = f2bf(v.z); l.z = f2bf(v.z - bf2f(h.z));
    h.w = f2bf(v.w); l.w = f2bf(v.w - bf2f(h.w));
    *(ushort4*)(hi + (size_t)i * 4) = h;
    *(ushort4*)(lo + (size_t)i * 4) = l;
  }
}

// ---------------------------------------------------------------------------
// Transpose fp32 [K][N] -> bf16 [N][K], plain.
// ---------------------------------------------------------------------------
__global__ __launch_bounds__(256) void transpose_to_bf16(const float* __restrict__ in,
                                                         unsigned short* __restrict__ out,
                                                         int K, int N) {
  __shared__ float t[64][65];
  const int n0 = blockIdx.x * 64;
  const int k0 = blockIdx.y * 64;
  const int tid = threadIdx.x;

  for (int idx = tid; idx < 64 * 16; idx += 256) {
    const int r = idx >> 4;
    const int c4 = (idx & 15) * 4;
    const float4 v = *(const float4*)(in + (size_t)(k0 + r) * N + n0 + c4);
    t[r][c4 + 0] = v.x; t[r][c4 + 1] = v.y; t[r][c4 + 2] = v.z; t[r][c4 + 3] = v.w;
  }
  __syncthreads();
  for (int idx = tid; idx < 64 * 16; idx += 256) {
    const int a = idx >> 4;
    const int b4 = (idx & 15) * 4;
    ushort4 u;
    u.x = f2bf(t[b4 + 0][a]); u.y = f2bf(t[b4 + 1][a]);
    u.z = f2bf(t[b4 + 2][a]); u.w = f2bf(t[b4 + 3][a]);
    *(ushort4*)(out + (size_t)(n0 + a) * K + k0 + b4) = u;
  }
}

// ---------------------------------------------------------------------------
// Transpose fp32 [K][N] -> split bf16 hi/lo [N][K].
// ---------------------------------------------------------------------------
__global__ __launch_bounds__(256) void transpose_to_bf16_split(const float* __restrict__ in,
                                                               unsigned short* __restrict__ ohi,
                                                               unsigned short* __restrict__ olo,
                                                               int K, int N) {
  __shared__ float t[64][65];
  const int n0 = blockIdx.x * 64;
  const int k0 = blockIdx.y * 64;
  const int tid = threadIdx.x;

  for (int idx = tid; idx < 64 * 16; idx += 256) {
    const int r = idx >> 4;
    const int c4 = (idx & 15) * 4;
    const float4 v = *(const float4*)(in + (size_t)(k0 + r) * N + n0 + c4);
    t[r][c4 + 0] = v.x; t[r][c4 + 1] = v.y; t[r][c4 + 2] = v.z; t[r][c4 + 3] = v.w;
  }
  __syncthreads();
  for (int idx = tid; idx < 64 * 16; idx += 256) {
    const int a = idx >> 4;
    const int b4 = (idx & 15) * 4;
    ushort4 h, l;
#pragma unroll
    for (int q = 0; q < 4; ++q) {
      const float v = t[b4 + q][a];
      const unsigned short hu = f2bf(v);
      const unsigned short lu = f2bf(v - bf2f(hu));
      ((unsigned short*)&h)[q] = hu;
      ((unsigned short*)&l)[q] = lu;
    }
    *(ushort4*)(ohi + (size_t)(n0 + a) * K + k0 + b4) = h;
    *(ushort4*)(olo + (size_t)(n0 + a) * K + k0 + b4) = l;
  }
}

// ---------------------------------------------------------------------------
// Plain bf16 MFMA GEMM (m97 structure): C[M][ldc] = A[M][K] * Bt[N][K]^T.
// 128x128 tile.
// ---------------------------------------------------------------------------
#define BM 128
#define BN 128
#define BK 32

template <typename OT>
__global__ __launch_bounds__(256) void gemm_bf16_bt(const unsigned short* __restrict__ A,
                                                    const unsigned short* __restrict__ Bt,
                                                    OT* __restrict__ C,
                                                    int M, int N, int K, int ldc) {
  __shared__ unsigned short As[BM * BK];
  __shared__ unsigned short Bs[BN * BK];

  const int tid = threadIdx.x;
  const int lane = tid & 63;
  const int wave = tid >> 6;
  const int m0 = blockIdx.y * BM;
  const int n0 = blockIdx.x * BN;

  const int qm = (wave >> 1) * 64;
  const int qn = (wave & 1) * 64;
  const int l15 = lane & 15;
  const int quad = lane >> 4;

  const int st_row = lane >> 2;
  const int st_col = (lane & 3) * 8;

  f32x4 acc[4][4] = {};

  for (int k0 = 0; k0 < K; k0 += BK) {
#pragma unroll
    for (int p = 0; p < 2; ++p) {
      const int rb = p * 64 + wave * 16;
      gload16(A + (size_t)(m0 + rb + st_row) * K + k0 + st_col, &As[rb * BK]);
      gload16(Bt + (size_t)(n0 + rb + st_row) * K + k0 + st_col, &Bs[rb * BK]);
    }
    __syncthreads();

    s16x8 a[4], b[4];
#pragma unroll
    for (int i = 0; i < 4; ++i)
      a[i] = *(const s16x8*)&As[(qm + i * 16 + l15) * BK + quad * 8];
#pragma unroll
    for (int j = 0; j < 4; ++j)
      b[j] = *(const s16x8*)&Bs[(qn + j * 16 + l15) * BK + quad * 8];
#pragma unroll
    for (int i = 0; i < 4; ++i)
#pragma unroll
      for (int j = 0; j < 4; ++j)
        acc[i][j] = __builtin_amdgcn_mfma_f32_16x16x32_bf16(a[i], b[j], acc[i][j], 0, 0, 0);
    __syncthreads();
  }

#pragma unroll
  for (int i = 0; i < 4; ++i) {
    const int row_base = m0 + qm + i * 16 + quad * 4;
#pragma unroll
    for (int j = 0; j < 4; ++j) {
      const int col = n0 + qn + j * 16 + l15;
#pragma unroll
      for (int r = 0; r < 4; ++r) {
        if constexpr (sizeof(OT) == 2)
          C[(size_t)(row_base + r) * ldc + col] = (OT)f2bf(acc[i][j][r]);
        else
          C[(size_t)(row_base + r) * ldc + col] = acc[i][j][r];
      }
    }
  }
}

// ---------------------------------------------------------------------------
// 128x64-tile bf16 MFMA GEMM for grid-starved shapes (V proj, wo proj).
// MODE 0: float C store. MODE 1: transposed bf16 store Ct[n][ldct]+m.
// ---------------------------------------------------------------------------
template <int MODE, typename OT>
__global__ __launch_bounds__(256) void gemm_bf16_bt64(const unsigned short* __restrict__ A,
                                                      const unsigned short* __restrict__ Bt,
                                                      OT* __restrict__ C,
                                                      int M, int N, int K, int ldc) {
  __shared__ unsigned short As[BM * BK];
  __shared__ unsigned short Bs[64 * BK];

  const int tid = threadIdx.x;
  const int lane = tid & 63;
  const int wave = tid >> 6;
  const int m0 = blockIdx.y * BM;
  const int n0 = blockIdx.x * 64;

  const int qm = (wave >> 1) * 64;
  const int qn = (wave & 1) * 32;
  const int l15 = lane & 15;
  const int quad = lane >> 4;

  const int st_row = lane >> 2;
  const int st_col = (lane & 3) * 8;

  f32x4 acc[4][2] = {};

  for (int k0 = 0; k0 < K; k0 += BK) {
#pragma unroll
    for (int p = 0; p < 2; ++p) {
      const int rb = p * 64 + wave * 16;
      gload16(A + (size_t)(m0 + rb + st_row) * K + k0 + st_col, &As[rb * BK]);
    }
    {
      const int rb = wave * 16;
      gload16(Bt + (size_t)(n0 + rb + st_row) * K + k0 + st_col, &Bs[rb * BK]);
    }
    __syncthreads();

    s16x8 a[4], b[2];
#pragma unroll
    for (int i = 0; i < 4; ++i)
      a[i] = *(const s16x8*)&As[(qm + i * 16 + l15) * BK + quad * 8];
#pragma unroll
    for (int j = 0; j < 2; ++j)
      b[j] = *(const s16x8*)&Bs[(qn + j * 16 + l15) * BK + quad * 8];
#pragma unroll
    for (int i = 0; i < 4; ++i)
#pragma unroll
      for (int j = 0; j < 2; ++j)
        acc[i][j] = __builtin_amdgcn_mfma_f32_16x16x32_bf16(a[i], b[j], acc[i][j], 0, 0, 0);
    __syncthreads();
  }

#pragma unroll
  for (int i = 0; i < 4; ++i) {
    const int row_base = m0 + qm + i * 16 + quad * 4;
#pragma unroll
    for (int j = 0; j < 2; ++j) {
      const int col = n0 + qn + j * 16 + l15;
      if constexpr (MODE == 0) {
#pragma unroll
        for (int r = 0; r < 4; ++r)
          C[(size_t)(row_base + r) * ldc + col] = acc[i][j][r];
      } else {
        ushort4 u;
        u.x = f2bf(acc[i][j][0]); u.y = f2bf(acc[i][j][1]);
        u.z = f2bf(acc[i][j][2]); u.w = f2bf(acc[i][j][3]);
        *(ushort4*)((unsigned short*)C + (size_t)col * ldc + row_base) = u;
      }
    }
  }
}

// ---------------------------------------------------------------------------
// Split-precision bf16 MFMA GEMM: C = (Ahi+Alo) * (Bhi+Blo)^T, dropping lo*lo.
// ---------------------------------------------------------------------------
__global__ __launch_bounds__(256) void gemm_split_bt(const unsigned short* __restrict__ Ahi,
                                                     const unsigned short* __restrict__ Alo,
                                                     const unsigned short* __restrict__ Bhi,
                                                     const unsigned short* __restrict__ Blo,
                                                     float* __restrict__ C,
                                                     int M, int N, int K, int ldc) {
  __shared__ unsigned short AsH[BM * BK];
  __shared__ unsigned short AsL[BM * BK];
  __shared__ unsigned short BsH[BN * BK];
  __shared__ unsigned short BsL[BN * BK];

  const int tid = threadIdx.x;
  const int lane = tid & 63;
  const int wave = tid >> 6;
  const int m0 = blockIdx.y * BM;
  const int n0 = blockIdx.x * BN;

  const int qm = (wave >> 1) * 64;
  const int qn = (wave & 1) * 64;
  const int l15 = lane & 15;
  const int quad = lane >> 4;

  const int st_row = lane >> 2;
  const int st_col = (lane & 3) * 8;

  f32x4 acc[4][4] = {};

  for (int k0 = 0; k0 < K; k0 += BK) {
#pragma unroll
    for (int p = 0; p < 2; ++p) {
      const int rb = p * 64 + wave * 16;
      const size_t aoff = (size_t)(m0 + rb + st_row) * K + k0 + st_col;
      const size_t boff = (size_t)(n0 + rb + st_row) * K + k0 + st_col;
      gload16(Ahi + aoff, &AsH[rb * BK]);
      gload16(Alo + aoff, &AsL[rb * BK]);
      gload16(Bhi + boff, &BsH[rb * BK]);
      gload16(Blo + boff, &BsL[rb * BK]);
    }
    __syncthreads();

    s16x8 ah[4], al[4], bh[4], bl[4];
#pragma unroll
    for (int i = 0; i < 4; ++i) {
      const int ro = (qm + i * 16 + l15) * BK + quad * 8;
      ah[i] = *(const s16x8*)&AsH[ro];
      al[i] = *(const s16x8*)&AsL[ro];
    }
#pragma unroll
    for (int j = 0; j < 4; ++j) {
      const int ro = (qn + j * 16 + l15) * BK + quad * 8;
      bh[j] = *(const s16x8*)&BsH[ro];
      bl[j] = *(const s16x8*)&BsL[ro];
    }
#pragma unroll
    for (int i = 0; i < 4; ++i)
#pragma unroll
      for (int j = 0; j < 4; ++j) {
        acc[i][j] = __builtin_amdgcn_mfma_f32_16x16x32_bf16(ah[i], bh[j], acc[i][j], 0, 0, 0);
        acc[i][j] = __builtin_amdgcn_mfma_f32_16x16x32_bf16(ah[i], bl[j], acc[i][j], 0, 0, 0);
        acc[i][j] = __builtin_amdgcn_mfma_f32_16x16x32_bf16(al[i], bh[j], acc[i][j], 0, 0, 0);
      }
    __syncthreads();
  }

#pragma unroll
  for (int i = 0; i < 4; ++i) {
    const int row_base = m0 + qm + i * 16 + quad * 4;
#pragma unroll
    for (int j = 0; j < 4; ++j) {
      const int col = n0 + qn + j * 16 + l15;
#pragma unroll
      for (int r = 0; r < 4; ++r)
        C[(size_t)(row_base + r) * ldc + col] = acc[i][j][r];
    }
  }
}

// ---------------------------------------------------------------------------
// Fused RMSNorm + RoPE, wave-per-row shfl version (no LDS, no barriers).
// ---------------------------------------------------------------------------
__global__ __launch_bounds__(256) void rmsnorm_rope_split(const float* __restrict__ qk,
                                                          const float* __restrict__ cosb,
                                                          const float* __restrict__ sinb,
                                                          unsigned short* __restrict__ qh,
                                                          unsigned short* __restrict__ ql,
                                                          unsigned short* __restrict__ kh,
                                                          unsigned short* __restrict__ kl) {
  const int s = blockIdx.x;
  const int wave = threadIdx.x >> 6;
  const int lane = threadIdx.x & 63;
  const int hh = blockIdx.y * 4 + wave;
  const bool is_q = (hh < 16);
  const int col = is_q ? hh * HD : 2048 + (hh - 16) * HD;

  const float* row = qk + (size_t)s * 3072 + col;
  const float x1 = row[lane];
  const float x2 = row[lane + 64];

  float ss = x1 * x1 + x2 * x2;
  ss += __shfl_xor(ss, 1);
  ss += __shfl_xor(ss, 2);
  ss += __shfl_xor(ss, 4);
  ss += __shfl_xor(ss, 8);
  ss += __shfl_xor(ss, 16);
  ss += __shfl_xor(ss, 32);
  const float r = rsqrtf(ss / 128.f + EPS);

  const float c = cosb[(size_t)s * HD + lane];
  const float sn = sinb[(size_t)s * HD + lane];
  float o1 = x1 * r * c - x2 * r * sn;   // d = lane
  float o2 = x2 * r * c + x1 * r * sn;   // d = lane + 64
  if (is_q) { o1 *= QK_SCALE; o2 *= QK_SCALE; }

  const unsigned short h1 = f2bf(o1), l1 = f2bf(o1 - bf2f(h1));
  const unsigned short h2 = f2bf(o2), l2 = f2bf(o2 - bf2f(h2));
  if (is_q) {
    const size_t base = (size_t)s * 2048 + hh * HD + lane;
    qh[base] = h1; ql[base] = l1;
    qh[base + 64] = h2; ql[base + 64] = l2;
  } else {
    const size_t base = (size_t)s * 1024 + (hh - 16) * HD + lane;
    kh[base] = h1; kl[base] = l1;
    kh[base + 64] = h2; kl[base + 64] = l2;
  }
}

// ---------------------------------------------------------------------------
// Flash attention, MFMA, single-buffer DMA + 2 blocks/CU (4 waves/SIMD).
// Post-mortem R2: dbuf pipeline was NEUTRAL (133.6 vs 128 us; MfmaUtil/
// VALUBusy unchanged) -- the staging drain was never the critical path.
// Both R0 and R2 ran at 8 waves/CU (2 waves/SIMD, Occupancy 22%): the real
// limiter is dependency-chain latency with too little TLP.
// This round: single K/V buffer (48KB) + Pt (10KB) = 59392 B LDS at
// 512 threads -> 2 blocks/CU -> 16 waves/CU -> 4 waves/SIMD (2x all prior
// rounds). Two barriers/tile return, but a co-resident independent block
// hides the drain (m114 cross-wave overlap). T13 defer-max + T5 setprio kept.
// ---------------------------------------------------------------------------
#define FA_N 64
#define FA_NT (S / FA_N)

__global__ __launch_bounds__(512, 4) void attn_flash_mfma(const unsigned short* __restrict__ qh,
                                                          const unsigned short* __restrict__ ql,
                                                          const unsigned short* __restrict__ kh,
                                                          const unsigned short* __restrict__ kl,
                                                          const unsigned short* __restrict__ vt,
                                                          unsigned short* __restrict__ out) {
  const int h = blockIdx.y;
  const int kvh = h >> 1;
  const int m0 = blockIdx.x * 64;
  const int tid = threadIdx.x;
  const int lane = tid & 63;
  const int wave = tid >> 6;   // 0..7
  const int rg = wave >> 1;    // row group (16 q-rows)
  const int kg = wave & 1;     // key half (32 of 64 keys)
  const int l15 = lane & 15;
  const int quad = lane >> 4;

  __shared__ char smem[59392];
  unsigned short* Kh = (unsigned short*)(smem);            // [64][128] u16, 16KB
  unsigned short* Kl = (unsigned short*)(smem + 16384);
  unsigned short* Vt = (unsigned short*)(smem + 32768);    // [128 d][64 keys]
  unsigned short* Pt = (unsigned short*)(smem + 49152) + wave * 640;  // [16][40]

  // ---- DMA staging: each wave stages 8 K-rows (hi+lo) and 16 V-rows ----
  auto STAGE = [&](int nt) {
#pragma unroll
    for (int p = 0; p < 2; ++p) {
      const int kr = wave * 8 + p * 4 + (lane >> 4);
      const size_t ksrc = (size_t)(nt + kr) * 1024 + kvh * HD + ((lane & 15) ^ (kr & 15)) * 8;
      gload16(kh + ksrc, Kh + (wave * 8 + p * 4) * 128);
      gload16(kl + ksrc, Kl + (wave * 8 + p * 4) * 128);
      const int d = wave * 16 + p * 8 + (lane >> 3);
      const size_t vsrc = (size_t)(kvh * HD + d) * 2048 + nt + ((lane & 7) ^ (d & 7)) * 8;
      gload16(vt + vsrc, Vt + (wave * 16 + p * 8) * 64);
    }
  };

  // ---- Q fragments in registers (A-layout), once ----
  s16x8 qah[4], qal[4];
  {
    const int qrow = m0 + rg * 16 + l15;
#pragma unroll
    for (int ks = 0; ks < 4; ++ks) {
      const size_t off = (size_t)qrow * 2048 + h * HD + ks * 32 + quad * 8;
      qah[ks] = *(const s16x8*)(qh + off);
      qal[ks] = *(const s16x8*)(ql + off);
    }
  }

  f32x4 O[8] = {};
  float m_i[4], l_i[4];
#pragma unroll
  for (int r = 0; r < 4; ++r) { m_i[r] = -1e30f; l_i[r] = 0.f; }

  for (int t = 0; t < FA_NT; ++t) {
    __syncthreads();  // previous tile's fragment reads done
    STAGE(t * FA_N);
    __syncthreads();  // DMA drained (vmcnt 0) + visible to all waves

    // ---- S = Q K^T over this wave's 32-key half, split precision ----
    f32x4 sacc[2] = {};
    __builtin_amdgcn_s_setprio(1);
#pragma unroll
    for (int ks = 0; ks < 4; ++ks) {
      s16x8 bh[2], bl[2];
#pragma unroll
      for (int j = 0; j < 2; ++j) {
        const int row = kg * 32 + j * 16 + l15;
        const int ro = row * 128 + (((ks * 4 + quad) ^ l15) * 8);
        bh[j] = *(const s16x8*)&Kh[ro];
        bl[j] = *(const s16x8*)&Kl[ro];
      }
#pragma unroll
      for (int j = 0; j < 2; ++j) {
        sacc[j] = __builtin_amdgcn_mfma_f32_16x16x32_bf16(qah[ks], bh[j], sacc[j], 0, 0, 0);
        sacc[j] = __builtin_amdgcn_mfma_f32_16x16x32_bf16(qah[ks], bl[j], sacc[j], 0, 0, 0);
        sacc[j] = __builtin_amdgcn_mfma_f32_16x16x32_bf16(qal[ks], bh[j], sacc[j], 0, 0, 0);
      }
    }
    __builtin_amdgcn_s_setprio(0);

    // ---- online softmax; T13 defer-max; l stays per-lane-partial ----
    float mt[4];
    float dmax = -1e30f;
#pragma unroll
    for (int r = 0; r < 4; ++r) {
      float m = fmaxf(sacc[0][r], sacc[1][r]);
      m = fmaxf(m, __shfl_xor(m, 1));
      m = fmaxf(m, __shfl_xor(m, 2));
      m = fmaxf(m, __shfl_xor(m, 4));
      m = fmaxf(m, __shfl_xor(m, 8));
      mt[r] = m;
      dmax = fmaxf(dmax, m - m_i[r]);
    }
    if (__any(dmax > 8.f)) {   // wave-uniform rescale path
#pragma unroll
      for (int r = 0; r < 4; ++r) {
        const float mnew = fmaxf(m_i[r], mt[r]);
        const float alpha = __expf(m_i[r] - mnew);
        m_i[r] = mnew;
        l_i[r] *= alpha;
#pragma unroll
        for (int jd = 0; jd < 8; ++jd) O[jd][r] *= alpha;
      }
    }
#pragma unroll
    for (int r = 0; r < 4; ++r) {
      const float p0 = __expf(sacc[0][r] - m_i[r]);
      const float p1 = __expf(sacc[1][r] - m_i[r]);
      l_i[r] += p0 + p1;
      const int prow = quad * 4 + r;
      Pt[prow * 40 + l15] = f2bf(p0);
      Pt[prow * 40 + 16 + l15] = f2bf(p1);
    }
    // no barrier: Pt is per-wave private; DS ops within a wave are ordered.

    // ---- O += P V over this wave's 32 keys ----
    const s16x8 pa = *(const s16x8*)&Pt[l15 * 40 + quad * 8];
    __builtin_amdgcn_s_setprio(1);
#pragma unroll
    for (int jd = 0; jd < 8; ++jd) {
      const int d = jd * 16 + l15;
      const int cp = ((kg * 4 + quad) ^ (d & 7)) * 8;
      const s16x8 vb = *(const s16x8*)&Vt[d * 64 + cp];
      O[jd] = __builtin_amdgcn_mfma_f32_16x16x32_bf16(pa, vb, O[jd], 0, 0, 0);
    }
    __builtin_amdgcn_s_setprio(0);
  }

  // ---- deferred l reduction (once instead of per tile) ----
#pragma unroll
  for (int r = 0; r < 4; ++r) {
    float ls = l_i[r];
    ls += __shfl_xor(ls, 1);
    ls += __shfl_xor(ls, 2);
    ls += __shfl_xor(ls, 4);
    ls += __shfl_xor(ls, 8);
    l_i[r] = ls;
  }

  // ---- merge the two key-halves per row group, then store ----
  __syncthreads();  // all fragment reads done; reuse LDS
  float* Om = (float*)smem;                 // [64 rows][128]
  float* ms = (float*)(smem + 32768);       // [64]
  float* ls2 = (float*)(smem + 33024);      // [64]

  if (kg == 1) {
#pragma unroll
    for (int r = 0; r < 4; ++r) {
      const int row = rg * 16 + quad * 4 + r;
      if (l15 == 0) { ms[row] = m_i[r]; ls2[row] = l_i[r]; }
#pragma unroll
      for (int jd = 0; jd < 8; ++jd)
        Om[(size_t)row * 128 + jd * 16 + l15] = O[jd][r];
    }
  }
  __syncthreads();
  if (kg == 0) {
#pragma unroll
    for (int r = 0; r < 4; ++r) {
      const int row = rg * 16 + quad * 4 + r;
      const float mB = ms[row];
      const float lB = ls2[row];
      const float mS = fmaxf(m_i[r], mB);
      const float aA = __expf(m_i[r] - mS);
      const float aB = __expf(mB - mS);
      const float inv = 1.f / (aA * l_i[r] + aB * lB);
      const int grow = m0 + row;
#pragma unroll
      for (int jd = 0; jd < 8; ++jd) {
        const float oB = Om[(size_t)row * 128 + jd * 16 + l15];
        out[(size_t)grow * 2048 + h * HD + jd * 16 + l15] =
            f2bf((aA * O[jd][r] + aB * oB) * inv);
      }
    }
  }
}

// ---------------------------------------------------------------------------
extern "C" void kernel_launch(void* const* d_in, const int* in_sizes, int n_in,
                              void* d_out, int out_size, void* d_ws, size_t ws_size,
                              hipStream_t stream) {
  const float* hidden = (const float*)d_in[0];  // [S][HID]
  const float* cosb   = (const float*)d_in[1];  // [S][HD]
  const float* sinb   = (const float*)d_in[2];  // [S][HD]
  const float* wq     = (const float*)d_in[3];  // [HID][2048]
  const float* wk     = (const float*)d_in[4];  // [HID][1024]
  const float* wv     = (const float*)d_in[5];  // [HID][1024]
  const float* wo     = (const float*)d_in[6];  // [2048][HID]
  float* out = (float*)d_out;                   // [S][HID]

  // Workspace map (72 MB, regions reused once dead):
  char* w = (char*)d_ws;
  float* qk_buf           = (float*)(w);                          //  0-24 MB fp32 [S][3072]
  unsigned short* wqkT_hi = (unsigned short*)(w + (24u << 20));   // 24-36 (dead after QK gemm)
  unsigned short* wqkT_lo = (unsigned short*)(w + (36u << 20));   // 36-48 (dead after QK gemm)
  unsigned short* hid_hi  = (unsigned short*)(w + (48u << 20));   // 48-56 (dead after V gemm)
  unsigned short* hid_lo  = (unsigned short*)(w + (56u << 20));   // 56-64 (dead after QK gemm)
  unsigned short* vt_b    = (unsigned short*)(w + (64u << 20));   // 64-68 V^T bf16 [1024][2048]
  unsigned short* wvT     = (unsigned short*)(w + (68u << 20));   // 68-72
  // reuse after QK gemm:
  unsigned short* q_hi    = (unsigned short*)(w + (24u << 20));   // 24-32 [S][2048]
  unsigned short* q_lo    = (unsigned short*)(w + (32u << 20));   // 32-40
  unsigned short* k_hi    = (unsigned short*)(w + (40u << 20));   // 40-44 [S][1024]
  unsigned short* k_lo    = (unsigned short*)(w + (44u << 20));   // 44-48
  // reuse after V gemm:
  unsigned short* woT     = (unsigned short*)(w + (48u << 20));   // 48-56 [2048][2048]
  unsigned short* a_b     = (unsigned short*)(w + (56u << 20));   // 56-64 [S][2048]

  dim3 blk(256);

  // prologue
  f32_to_bf16_split<<<dim3((S * HID / 4 + 255) / 256), blk, 0, stream>>>(hidden, hid_hi, hid_lo, S * HID / 4);
  transpose_to_bf16_split<<<dim3(32, 32), blk, 0, stream>>>(wq, wqkT_hi, wqkT_lo, HID, 2048);
  transpose_to_bf16_split<<<dim3(16, 32), blk, 0, stream>>>(wk, wqkT_hi + (size_t)2048 * 2048,
                                                            wqkT_lo + (size_t)2048 * 2048, HID, 1024);
  transpose_to_bf16<<<dim3(16, 32), blk, 0, stream>>>(wv, wvT, 2048, 1024);

  // QK projection (split precision) -> fp32 [S][3072]
  gemm_split_bt<<<dim3(3072 / BN, S / BM), blk, 0, stream>>>(hid_hi, hid_lo, wqkT_hi, wqkT_lo,
                                                             qk_buf, S, 3072, HID, 3072);

  // V projection -> transposed bf16 [1024][2048]; 128x64 tile, 256 blocks
  gemm_bf16_bt64<1, unsigned short><<<dim3(1024 / 64, S / BM), blk, 0, stream>>>(
      hid_hi, wvT, vt_b, S, 1024, HID, 2048);

  // wo transpose into dead hid_hi region (after V gemm in stream order)
  transpose_to_bf16<<<dim3(32, 32), blk, 0, stream>>>(wo, woT, 2048, HID);

  // RMSNorm + RoPE -> split bf16 q/k (q pre-scaled); wave-per-row
  rmsnorm_rope_split<<<dim3(S, 6), blk, 0, stream>>>(qk_buf, cosb, sinb, q_hi, q_lo, k_hi, k_lo);

  // MFMA flash attention (512 thr, 2 blocks/CU, 4 waves/SIMD) -> bf16 [S][2048]
  attn_flash_mfma<<<dim3(S / 64, NH), dim3(512), 0, stream>>>(q_hi, q_lo, k_hi, k_lo, vt_b, a_b);

  // output projection -> fp32 out; 128x64 tile, 512 blocks
  gemm_bf16_bt64<0, float><<<dim3(HID / 64, S / BM), blk, 0, stream>>>(
      a_b, woT, out, S, HID, 2048, HID);
}

// Round 4
// 385.929 us; speedup vs baseline: 1.3630x; 1.0340x over previous
//
#include <hip/hip_runtime.h>
#include <hip/hip_bf16.h>
#include <math.h>

// Problem constants
#define S 2048
#define HID 2048
#define NH 16
#define KVH 8
#define HD 128
#define EPS 1e-6f
#define QK_SCALE 11.313708498984760390f  // 1/SCALING = sqrt(128)

typedef __attribute__((ext_vector_type(8))) short s16x8;
typedef __attribute__((ext_vector_type(4))) float f32x4;

__device__ __forceinline__ unsigned short f2bf(float f) {
  __hip_bfloat16 h = __float2bfloat16(f);
  return *(unsigned short*)&h;
}
__device__ __forceinline__ float bf2f(unsigned short u) {
  unsigned int x = ((unsigned int)u) << 16;
  return __builtin_bit_cast(float, x);
}

__device__ __forceinline__ void gload16(const void* g, void* l) {
  __builtin_amdgcn_global_load_lds(
      (const __attribute__((address_space(1))) void*)g,
      (__attribute__((address_space(3))) void*)l, 16, 0, 0);
}

// ---------------------------------------------------------------------------
// fp32 -> split bf16 (hi + lo) elementwise.
// ---------------------------------------------------------------------------
__global__ __launch_bounds__(256) void f32_to_bf16_split(const float* __restrict__ in,
                                                         unsigned short* __restrict__ hi,
                                                         unsigned short* __restrict__ lo,
                                                         int n4) {
  const int i = blockIdx.x * 256 + threadIdx.x;
  if (i < n4) {
    const float4 v = *(const float4*)(in + (size_t)i * 4);
    ushort4 h, l;
    h.x = f2bf(v.x); l.x = f2bf(v.x - bf2f(h.x));
    h.y = f2bf(v.y); l.y = f2bf(v.y - bf2f(h.y));
    h.z = f2bf(v.z); l.z = f2bf(v.z - bf2f(h.z));
    h.w = f2bf(v.w); l.w = f2bf(v.w - bf2f(h.w));
    *(ushort4*)(hi + (size_t)i * 4) = h;
    *(ushort4*)(lo + (size_t)i * 4) = l;
  }
}

// ---------------------------------------------------------------------------
// Transpose fp32 [K][N] -> bf16 [N][K], plain.
// ---------------------------------------------------------------------------
__global__ __launch_bounds__(256) void transpose_to_bf16(const float* __restrict__ in,
                                                         unsigned short* __restrict__ out,
                                                         int K, int N) {
  __shared__ float t[64][65];
  const int n0 = blockIdx.x * 64;
  const int k0 = blockIdx.y * 64;
  const int tid = threadIdx.x;

  for (int idx = tid; idx < 64 * 16; idx += 256) {
    const int r = idx >> 4;
    const int c4 = (idx & 15) * 4;
    const float4 v = *(const float4*)(in + (size_t)(k0 + r) * N + n0 + c4);
    t[r][c4 + 0] = v.x; t[r][c4 + 1] = v.y; t[r][c4 + 2] = v.z; t[r][c4 + 3] = v.w;
  }
  __syncthreads();
  for (int idx = tid; idx < 64 * 16; idx += 256) {
    const int a = idx >> 4;
    const int b4 = (idx & 15) * 4;
    ushort4 u;
    u.x = f2bf(t[b4 + 0][a]); u.y = f2bf(t[b4 + 1][a]);
    u.z = f2bf(t[b4 + 2][a]); u.w = f2bf(t[b4 + 3][a]);
    *(ushort4*)(out + (size_t)(n0 + a) * K + k0 + b4) = u;
  }
}

// ---------------------------------------------------------------------------
// Transpose fp32 [K][N] -> split bf16 hi/lo [N][K].
// ---------------------------------------------------------------------------
__global__ __launch_bounds__(256) void transpose_to_bf16_split(const float* __restrict__ in,
                                                               unsigned short* __restrict__ ohi,
                                                               unsigned short* __restrict__ olo,
                                                               int K, int N) {
  __shared__ float t[64][65];
  const int n0 = blockIdx.x * 64;
  const int k0 = blockIdx.y * 64;
  const int tid = threadIdx.x;

  for (int idx = tid; idx < 64 * 16; idx += 256) {
    const int r = idx >> 4;
    const int c4 = (idx & 15) * 4;
    const float4 v = *(const float4*)(in + (size_t)(k0 + r) * N + n0 + c4);
    t[r][c4 + 0] = v.x; t[r][c4 + 1] = v.y; t[r][c4 + 2] = v.z; t[r][c4 + 3] = v.w;
  }
  __syncthreads();
  for (int idx = tid; idx < 64 * 16; idx += 256) {
    const int a = idx >> 4;
    const int b4 = (idx & 15) * 4;
    ushort4 h, l;
#pragma unroll
    for (int q = 0; q < 4; ++q) {
      const float v = t[b4 + q][a];
      const unsigned short hu = f2bf(v);
      const unsigned short lu = f2bf(v - bf2f(hu));
      ((unsigned short*)&h)[q] = hu;
      ((unsigned short*)&l)[q] = lu;
    }
    *(ushort4*)(ohi + (size_t)(n0 + a) * K + k0 + b4) = h;
    *(ushort4*)(olo + (size_t)(n0 + a) * K + k0 + b4) = l;
  }
}

#define BK 32

// ---------------------------------------------------------------------------
// Split-precision bf16 MFMA GEMM, 128x64 tile: C = (Ahi+Alo)(Bhi+Blo)^T minus
// lo*lo. Round 4: replaces the 128x128 version whose 384-block grid left half
// the chip idle every other round (1.5 blocks/CU). 768 blocks = 3/CU even;
// LDS 24KB -> 3+ resident.
// ---------------------------------------------------------------------------
__global__ __launch_bounds__(256) void gemm_split_bt64(const unsigned short* __restrict__ Ahi,
                                                       const unsigned short* __restrict__ Alo,
                                                       const unsigned short* __restrict__ Bhi,
                                                       const unsigned short* __restrict__ Blo,
                                                       float* __restrict__ C,
                                                       int M, int N, int K, int ldc) {
  __shared__ unsigned short AsH[128 * BK];
  __shared__ unsigned short AsL[128 * BK];
  __shared__ unsigned short BsH[64 * BK];
  __shared__ unsigned short BsL[64 * BK];

  const int tid = threadIdx.x;
  const int lane = tid & 63;
  const int wave = tid >> 6;
  const int m0 = blockIdx.y * 128;
  const int n0 = blockIdx.x * 64;

  const int qm = (wave >> 1) * 64;
  const int qn = (wave & 1) * 32;
  const int l15 = lane & 15;
  const int quad = lane >> 4;

  const int st_row = lane >> 2;
  const int st_col = (lane & 3) * 8;

  f32x4 acc[4][2] = {};

  for (int k0 = 0; k0 < K; k0 += BK) {
#pragma unroll
    for (int p = 0; p < 2; ++p) {
      const int rb = p * 64 + wave * 16;
      const size_t aoff = (size_t)(m0 + rb + st_row) * K + k0 + st_col;
      gload16(Ahi + aoff, &AsH[rb * BK]);
      gload16(Alo + aoff, &AsL[rb * BK]);
    }
    {
      const int rb = wave * 16;
      const size_t boff = (size_t)(n0 + rb + st_row) * K + k0 + st_col;
      gload16(Bhi + boff, &BsH[rb * BK]);
      gload16(Blo + boff, &BsL[rb * BK]);
    }
    __syncthreads();

    s16x8 ah[4], al[4], bh[2], bl[2];
#pragma unroll
    for (int i = 0; i < 4; ++i) {
      const int ro = (qm + i * 16 + l15) * BK + quad * 8;
      ah[i] = *(const s16x8*)&AsH[ro];
      al[i] = *(const s16x8*)&AsL[ro];
    }
#pragma unroll
    for (int j = 0; j < 2; ++j) {
      const int ro = (qn + j * 16 + l15) * BK + quad * 8;
      bh[j] = *(const s16x8*)&BsH[ro];
      bl[j] = *(const s16x8*)&BsL[ro];
    }
#pragma unroll
    for (int i = 0; i < 4; ++i)
#pragma unroll
      for (int j = 0; j < 2; ++j) {
        acc[i][j] = __builtin_amdgcn_mfma_f32_16x16x32_bf16(ah[i], bh[j], acc[i][j], 0, 0, 0);
        acc[i][j] = __builtin_amdgcn_mfma_f32_16x16x32_bf16(ah[i], bl[j], acc[i][j], 0, 0, 0);
        acc[i][j] = __builtin_amdgcn_mfma_f32_16x16x32_bf16(al[i], bh[j], acc[i][j], 0, 0, 0);
      }
    __syncthreads();
  }

#pragma unroll
  for (int i = 0; i < 4; ++i) {
    const int row_base = m0 + qm + i * 16 + quad * 4;
#pragma unroll
    for (int j = 0; j < 2; ++j) {
      const int col = n0 + qn + j * 16 + l15;
#pragma unroll
      for (int r = 0; r < 4; ++r)
        C[(size_t)(row_base + r) * ldc + col] = acc[i][j][r];
    }
  }
}

// ---------------------------------------------------------------------------
// 64x64-tile plain bf16 MFMA GEMM. Round 4: replaces the 128x64 version for
// V proj (was 256 blocks = 1/CU = 1 wave/SIMD!) and wo proj (512 = 2/CU).
// V proj: 512 blocks = 2/CU even. wo proj: 1024 blocks = 4/CU.
// MODE 0: float C store. MODE 1: transposed bf16 store Ct[n][ldct]+m.
// ---------------------------------------------------------------------------
template <int MODE, typename OT>
__global__ __launch_bounds__(256) void gemm_bf16_6464(const unsigned short* __restrict__ A,
                                                      const unsigned short* __restrict__ Bt,
                                                      OT* __restrict__ C,
                                                      int M, int N, int K, int ldc) {
  __shared__ unsigned short As[64 * BK];
  __shared__ unsigned short Bs[64 * BK];

  const int tid = threadIdx.x;
  const int lane = tid & 63;
  const int wave = tid >> 6;
  const int m0 = blockIdx.y * 64;
  const int n0 = blockIdx.x * 64;

  const int qm = (wave >> 1) * 32;
  const int qn = (wave & 1) * 32;
  const int l15 = lane & 15;
  const int quad = lane >> 4;

  const int st_row = lane >> 2;
  const int st_col = (lane & 3) * 8;

  f32x4 acc[2][2] = {};

  for (int k0 = 0; k0 < K; k0 += BK) {
    {
      const int rb = wave * 16;
      gload16(A + (size_t)(m0 + rb + st_row) * K + k0 + st_col, &As[rb * BK]);
      gload16(Bt + (size_t)(n0 + rb + st_row) * K + k0 + st_col, &Bs[rb * BK]);
    }
    __syncthreads();

    s16x8 a[2], b[2];
#pragma unroll
    for (int i = 0; i < 2; ++i)
      a[i] = *(const s16x8*)&As[(qm + i * 16 + l15) * BK + quad * 8];
#pragma unroll
    for (int j = 0; j < 2; ++j)
      b[j] = *(const s16x8*)&Bs[(qn + j * 16 + l15) * BK + quad * 8];
#pragma unroll
    for (int i = 0; i < 2; ++i)
#pragma unroll
      for (int j = 0; j < 2; ++j)
        acc[i][j] = __builtin_amdgcn_mfma_f32_16x16x32_bf16(a[i], b[j], acc[i][j], 0, 0, 0);
    __syncthreads();
  }

#pragma unroll
  for (int i = 0; i < 2; ++i) {
    const int row_base = m0 + qm + i * 16 + quad * 4;
#pragma unroll
    for (int j = 0; j < 2; ++j) {
      const int col = n0 + qn + j * 16 + l15;
      if constexpr (MODE == 0) {
#pragma unroll
        for (int r = 0; r < 4; ++r)
          C[(size_t)(row_base + r) * ldc + col] = acc[i][j][r];
      } else {
        ushort4 u;
        u.x = f2bf(acc[i][j][0]); u.y = f2bf(acc[i][j][1]);
        u.z = f2bf(acc[i][j][2]); u.w = f2bf(acc[i][j][3]);
        *(ushort4*)((unsigned short*)C + (size_t)col * ldc + row_base) = u;
      }
    }
  }
}

// ---------------------------------------------------------------------------
// Fused RMSNorm + RoPE, wave-per-row shfl version (no LDS, no barriers).
// ---------------------------------------------------------------------------
__global__ __launch_bounds__(256) void rmsnorm_rope_split(const float* __restrict__ qk,
                                                          const float* __restrict__ cosb,
                                                          const float* __restrict__ sinb,
                                                          unsigned short* __restrict__ qh,
                                                          unsigned short* __restrict__ ql,
                                                          unsigned short* __restrict__ kh,
                                                          unsigned short* __restrict__ kl) {
  const int s = blockIdx.x;
  const int wave = threadIdx.x >> 6;
  const int lane = threadIdx.x & 63;
  const int hh = blockIdx.y * 4 + wave;
  const bool is_q = (hh < 16);
  const int col = is_q ? hh * HD : 2048 + (hh - 16) * HD;

  const float* row = qk + (size_t)s * 3072 + col;
  const float x1 = row[lane];
  const float x2 = row[lane + 64];

  float ss = x1 * x1 + x2 * x2;
  ss += __shfl_xor(ss, 1);
  ss += __shfl_xor(ss, 2);
  ss += __shfl_xor(ss, 4);
  ss += __shfl_xor(ss, 8);
  ss += __shfl_xor(ss, 16);
  ss += __shfl_xor(ss, 32);
  const float r = rsqrtf(ss / 128.f + EPS);

  const float c = cosb[(size_t)s * HD + lane];
  const float sn = sinb[(size_t)s * HD + lane];
  float o1 = x1 * r * c - x2 * r * sn;   // d = lane
  float o2 = x2 * r * c + x1 * r * sn;   // d = lane + 64
  if (is_q) { o1 *= QK_SCALE; o2 *= QK_SCALE; }

  const unsigned short h1 = f2bf(o1), l1 = f2bf(o1 - bf2f(h1));
  const unsigned short h2 = f2bf(o2), l2 = f2bf(o2 - bf2f(h2));
  if (is_q) {
    const size_t base = (size_t)s * 2048 + hh * HD + lane;
    qh[base] = h1; ql[base] = l1;
    qh[base + 64] = h2; ql[base + 64] = l2;
  } else {
    const size_t base = (size_t)s * 1024 + (hh - 16) * HD + lane;
    kh[base] = h1; kl[base] = l1;
    kh[base + 64] = h2; kl[base + 64] = l2;
  }
}

// ---------------------------------------------------------------------------
// Flash attention, MFMA, single-buffer DMA + 2 blocks/CU (4 waves/SIMD).
// (Unchanged from round 3: 110.4 us, Occupancy 39.5%, MfmaUtil 26.)
// ---------------------------------------------------------------------------
#define FA_N 64
#define FA_NT (S / FA_N)

__global__ __launch_bounds__(512, 4) void attn_flash_mfma(const unsigned short* __restrict__ qh,
                                                          const unsigned short* __restrict__ ql,
                                                          const unsigned short* __restrict__ kh,
                                                          const unsigned short* __restrict__ kl,
                                                          const unsigned short* __restrict__ vt,
                                                          unsigned short* __restrict__ out) {
  const int h = blockIdx.y;
  const int kvh = h >> 1;
  const int m0 = blockIdx.x * 64;
  const int tid = threadIdx.x;
  const int lane = tid & 63;
  const int wave = tid >> 6;   // 0..7
  const int rg = wave >> 1;    // row group (16 q-rows)
  const int kg = wave & 1;     // key half (32 of 64 keys)
  const int l15 = lane & 15;
  const int quad = lane >> 4;

  __shared__ char smem[59392];
  unsigned short* Kh = (unsigned short*)(smem);            // [64][128] u16, 16KB
  unsigned short* Kl = (unsigned short*)(smem + 16384);
  unsigned short* Vt = (unsigned short*)(smem + 32768);    // [128 d][64 keys]
  unsigned short* Pt = (unsigned short*)(smem + 49152) + wave * 640;  // [16][40]

  // ---- DMA staging: each wave stages 8 K-rows (hi+lo) and 16 V-rows ----
  auto STAGE = [&](int nt) {
#pragma unroll
    for (int p = 0; p < 2; ++p) {
      const int kr = wave * 8 + p * 4 + (lane >> 4);
      const size_t ksrc = (size_t)(nt + kr) * 1024 + kvh * HD + ((lane & 15) ^ (kr & 15)) * 8;
      gload16(kh + ksrc, Kh + (wave * 8 + p * 4) * 128);
      gload16(kl + ksrc, Kl + (wave * 8 + p * 4) * 128);
      const int d = wave * 16 + p * 8 + (lane >> 3);
      const size_t vsrc = (size_t)(kvh * HD + d) * 2048 + nt + ((lane & 7) ^ (d & 7)) * 8;
      gload16(vt + vsrc, Vt + (wave * 16 + p * 8) * 64);
    }
  };

  // ---- Q fragments in registers (A-layout), once ----
  s16x8 qah[4], qal[4];
  {
    const int qrow = m0 + rg * 16 + l15;
#pragma unroll
    for (int ks = 0; ks < 4; ++ks) {
      const size_t off = (size_t)qrow * 2048 + h * HD + ks * 32 + quad * 8;
      qah[ks] = *(const s16x8*)(qh + off);
      qal[ks] = *(const s16x8*)(ql + off);
    }
  }

  f32x4 O[8] = {};
  float m_i[4], l_i[4];
#pragma unroll
  for (int r = 0; r < 4; ++r) { m_i[r] = -1e30f; l_i[r] = 0.f; }

  for (int t = 0; t < FA_NT; ++t) {
    __syncthreads();  // previous tile's fragment reads done
    STAGE(t * FA_N);
    __syncthreads();  // DMA drained (vmcnt 0) + visible to all waves

    // ---- S = Q K^T over this wave's 32-key half, split precision ----
    f32x4 sacc[2] = {};
    __builtin_amdgcn_s_setprio(1);
#pragma unroll
    for (int ks = 0; ks < 4; ++ks) {
      s16x8 bh[2], bl[2];
#pragma unroll
      for (int j = 0; j < 2; ++j) {
        const int row = kg * 32 + j * 16 + l15;
        const int ro = row * 128 + (((ks * 4 + quad) ^ l15) * 8);
        bh[j] = *(const s16x8*)&Kh[ro];
        bl[j] = *(const s16x8*)&Kl[ro];
      }
#pragma unroll
      for (int j = 0; j < 2; ++j) {
        sacc[j] = __builtin_amdgcn_mfma_f32_16x16x32_bf16(qah[ks], bh[j], sacc[j], 0, 0, 0);
        sacc[j] = __builtin_amdgcn_mfma_f32_16x16x32_bf16(qah[ks], bl[j], sacc[j], 0, 0, 0);
        sacc[j] = __builtin_amdgcn_mfma_f32_16x16x32_bf16(qal[ks], bh[j], sacc[j], 0, 0, 0);
      }
    }
    __builtin_amdgcn_s_setprio(0);

    // ---- online softmax; T13 defer-max; l stays per-lane-partial ----
    float mt[4];
    float dmax = -1e30f;
#pragma unroll
    for (int r = 0; r < 4; ++r) {
      float m = fmaxf(sacc[0][r], sacc[1][r]);
      m = fmaxf(m, __shfl_xor(m, 1));
      m = fmaxf(m, __shfl_xor(m, 2));
      m = fmaxf(m, __shfl_xor(m, 4));
      m = fmaxf(m, __shfl_xor(m, 8));
      mt[r] = m;
      dmax = fmaxf(dmax, m - m_i[r]);
    }
    if (__any(dmax > 8.f)) {   // wave-uniform rescale path
#pragma unroll
      for (int r = 0; r < 4; ++r) {
        const float mnew = fmaxf(m_i[r], mt[r]);
        const float alpha = __expf(m_i[r] - mnew);
        m_i[r] = mnew;
        l_i[r] *= alpha;
#pragma unroll
        for (int jd = 0; jd < 8; ++jd) O[jd][r] *= alpha;
      }
    }
#pragma unroll
    for (int r = 0; r < 4; ++r) {
      const float p0 = __expf(sacc[0][r] - m_i[r]);
      const float p1 = __expf(sacc[1][r] - m_i[r]);
      l_i[r] += p0 + p1;
      const int prow = quad * 4 + r;
      Pt[prow * 40 + l15] = f2bf(p0);
      Pt[prow * 40 + 16 + l15] = f2bf(p1);
    }
    // no barrier: Pt is per-wave private; DS ops within a wave are ordered.

    // ---- O += P V over this wave's 32 keys ----
    const s16x8 pa = *(const s16x8*)&Pt[l15 * 40 + quad * 8];
    __builtin_amdgcn_s_setprio(1);
#pragma unroll
    for (int jd = 0; jd < 8; ++jd) {
      const int d = jd * 16 + l15;
      const int cp = ((kg * 4 + quad) ^ (d & 7)) * 8;
      const s16x8 vb = *(const s16x8*)&Vt[d * 64 + cp];
      O[jd] = __builtin_amdgcn_mfma_f32_16x16x32_bf16(pa, vb, O[jd], 0, 0, 0);
    }
    __builtin_amdgcn_s_setprio(0);
  }

  // ---- deferred l reduction (once instead of per tile) ----
#pragma unroll
  for (int r = 0; r < 4; ++r) {
    float ls = l_i[r];
    ls += __shfl_xor(ls, 1);
    ls += __shfl_xor(ls, 2);
    ls += __shfl_xor(ls, 4);
    ls += __shfl_xor(ls, 8);
    l_i[r] = ls;
  }

  // ---- merge the two key-halves per row group, then store ----
  __syncthreads();  // all fragment reads done; reuse LDS
  float* Om = (float*)smem;                 // [64 rows][128]
  float* ms = (float*)(smem + 32768);       // [64]
  float* ls2 = (float*)(smem + 33024);      // [64]

  if (kg == 1) {
#pragma unroll
    for (int r = 0; r < 4; ++r) {
      const int row = rg * 16 + quad * 4 + r;
      if (l15 == 0) { ms[row] = m_i[r]; ls2[row] = l_i[r]; }
#pragma unroll
      for (int jd = 0; jd < 8; ++jd)
        Om[(size_t)row * 128 + jd * 16 + l15] = O[jd][r];
    }
  }
  __syncthreads();
  if (kg == 0) {
#pragma unroll
    for (int r = 0; r < 4; ++r) {
      const int row = rg * 16 + quad * 4 + r;
      const float mB = ms[row];
      const float lB = ls2[row];
      const float mS = fmaxf(m_i[r], mB);
      const float aA = __expf(m_i[r] - mS);
      const float aB = __expf(mB - mS);
      const float inv = 1.f / (aA * l_i[r] + aB * lB);
      const int grow = m0 + row;
#pragma unroll
      for (int jd = 0; jd < 8; ++jd) {
        const float oB = Om[(size_t)row * 128 + jd * 16 + l15];
        out[(size_t)grow * 2048 + h * HD + jd * 16 + l15] =
            f2bf((aA * O[jd][r] + aB * oB) * inv);
      }
    }
  }
}

// ---------------------------------------------------------------------------
extern "C" void kernel_launch(void* const* d_in, const int* in_sizes, int n_in,
                              void* d_out, int out_size, void* d_ws, size_t ws_size,
                              hipStream_t stream) {
  const float* hidden = (const float*)d_in[0];  // [S][HID]
  const float* cosb   = (const float*)d_in[1];  // [S][HD]
  const float* sinb   = (const float*)d_in[2];  // [S][HD]
  const float* wq     = (const float*)d_in[3];  // [HID][2048]
  const float* wk     = (const float*)d_in[4];  // [HID][1024]
  const float* wv     = (const float*)d_in[5];  // [HID][1024]
  const float* wo     = (const float*)d_in[6];  // [2048][HID]
  float* out = (float*)d_out;                   // [S][HID]

  // Workspace map (72 MB, regions reused once dead):
  char* w = (char*)d_ws;
  float* qk_buf           = (float*)(w);                          //  0-24 MB fp32 [S][3072]
  unsigned short* wqkT_hi = (unsigned short*)(w + (24u << 20));   // 24-36 (dead after QK gemm)
  unsigned short* wqkT_lo = (unsigned short*)(w + (36u << 20));   // 36-48 (dead after QK gemm)
  unsigned short* hid_hi  = (unsigned short*)(w + (48u << 20));   // 48-56 (dead after V gemm)
  unsigned short* hid_lo  = (unsigned short*)(w + (56u << 20));   // 56-64 (dead after QK gemm)
  unsigned short* vt_b    = (unsigned short*)(w + (64u << 20));   // 64-68 V^T bf16 [1024][2048]
  unsigned short* wvT     = (unsigned short*)(w + (68u << 20));   // 68-72
  // reuse after QK gemm:
  unsigned short* q_hi    = (unsigned short*)(w + (24u << 20));   // 24-32 [S][2048]
  unsigned short* q_lo    = (unsigned short*)(w + (32u << 20));   // 32-40
  unsigned short* k_hi    = (unsigned short*)(w + (40u << 20));   // 40-44 [S][1024]
  unsigned short* k_lo    = (unsigned short*)(w + (44u << 20));   // 44-48
  // reuse after V gemm:
  unsigned short* woT     = (unsigned short*)(w + (48u << 20));   // 48-56 [2048][2048]
  unsigned short* a_b     = (unsigned short*)(w + (56u << 20));   // 56-64 [S][2048]

  dim3 blk(256);

  // prologue
  f32_to_bf16_split<<<dim3((S * HID / 4 + 255) / 256), blk, 0, stream>>>(hidden, hid_hi, hid_lo, S * HID / 4);
  transpose_to_bf16_split<<<dim3(32, 32), blk, 0, stream>>>(wq, wqkT_hi, wqkT_lo, HID, 2048);
  transpose_to_bf16_split<<<dim3(16, 32), blk, 0, stream>>>(wk, wqkT_hi + (size_t)2048 * 2048,
                                                            wqkT_lo + (size_t)2048 * 2048, HID, 1024);
  transpose_to_bf16<<<dim3(16, 32), blk, 0, stream>>>(wv, wvT, 2048, 1024);

  // QK projection (split precision) -> fp32 [S][3072]; 128x64 tile,
  // 768 blocks = 3/CU even (was 384 = 1.5/CU imbalanced)
  gemm_split_bt64<<<dim3(3072 / 64, S / 128), blk, 0, stream>>>(hid_hi, hid_lo, wqkT_hi, wqkT_lo,
                                                                qk_buf, S, 3072, HID, 3072);

  // V projection -> transposed bf16 [1024][2048]; 64x64 tile, 512 blocks = 2/CU
  // (was 256 = 1/CU, 1 wave/SIMD)
  gemm_bf16_6464<1, unsigned short><<<dim3(1024 / 64, S / 64), blk, 0, stream>>>(
      hid_hi, wvT, vt_b, S, 1024, HID, 2048);

  // wo transpose into dead hid_hi region (after V gemm in stream order)
  transpose_to_bf16<<<dim3(32, 32), blk, 0, stream>>>(wo, woT, 2048, HID);

  // RMSNorm + RoPE -> split bf16 q/k (q pre-scaled); wave-per-row
  rmsnorm_rope_split<<<dim3(S, 6), blk, 0, stream>>>(qk_buf, cosb, sinb, q_hi, q_lo, k_hi, k_lo);

  // MFMA flash attention (512 thr, 2 blocks/CU, 4 waves/SIMD) -> bf16 [S][2048]
  attn_flash_mfma<<<dim3(S / 64, NH), dim3(512), 0, stream>>>(q_hi, q_lo, k_hi, k_lo, vt_b, a_b);

  // output projection -> fp32 out; 64x64 tile, 1024 blocks = 4/CU (was 512 = 2/CU)
  gemm_bf16_6464<0, float><<<dim3(HID / 64, S / 64), blk, 0, stream>>>(
      a_b, woT, out, S, HID, 2048, HID);
}